// Round 8
// baseline (1033.859 us; speedup 1.0000x reference)
//
#include <hip/hip_runtime.h>
#include <hip/hip_bf16.h>
#include <math.h>

// Problem constants
#define GG 33538
#define DD 256
#define LL 6
#define HH 8
#define KK 2048
#define BB 4
#define TT 2049          // K+1 tokens
#define BT (BB*TT)       // 8196
#define NT 65            // 32-key tiles per (b,h)
#define TCH 7            // topk blocks per batch row (7*5120 >= GG)
#define QSC (0.17677669529663688f * 1.44269504088896340f)   // 1/sqrt(32) * log2e

typedef __bf16 bf16x8 __attribute__((ext_vector_type(8)));
typedef float f32x4 __attribute__((ext_vector_type(4)));
typedef float f32x16 __attribute__((ext_vector_type(16)));
typedef unsigned short ub16;

union BW { __bf16 h; ub16 u; };
__device__ __forceinline__ ub16 f2b(float x) { BW w; w.h = (__bf16)x; return w.u; }
__device__ __forceinline__ unsigned pk2(float a, float b) {
    return (unsigned)f2b(a) | ((unsigned)f2b(b) << 16);
}
union U4B { unsigned u[4]; bf16x8 v; };

__device__ __forceinline__ float gelu_f(float x) {
    return 0.5f * x * (1.0f + erff(x * 0.70710678118654752440f));
}

__device__ __forceinline__ unsigned to_key(float x) {
    unsigned u = __float_as_uint(x);
    return (u & 0x80000000u) ? ~u : (u | 0x80000000u);
}

// ---------------- Top-K phase kernels (multi-block radix select) ----------------
__device__ int block_scan_excl_1024(int v, int* shw) {
    int lane = threadIdx.x & 63, w = threadIdx.x >> 6;
    int x = v;
    #pragma unroll
    for (int o = 1; o < 64; o <<= 1) {
        int t = __shfl_up(x, o, 64);
        if (lane >= o) x += t;
    }
    if (lane == 63) shw[w] = x;
    __syncthreads();
    if (w == 0) {
        int y = (lane < 16) ? shw[lane] : 0;
        #pragma unroll
        for (int o = 1; o < 16; o <<= 1) {
            int t = __shfl_up(y, o, 64);
            if (lane >= o) y += t;
        }
        if (lane < 16) shw[lane] = y;
    }
    __syncthreads();
    int off = (w == 0) ? 0 : shw[w - 1];
    return off + x - v;   // exclusive prefix
}

__global__ void topk_init(unsigned* __restrict__ prefwant, unsigned* __restrict__ histg) {
    int i = threadIdx.x;
    if (i < BB * 256) histg[i] = 0u;
    if (i < BB) { prefwant[2 * i] = 0u; prefwant[2 * i + 1] = KK; }
}

__global__ __launch_bounds__(1024) void topk_hist(const float* __restrict__ expr,
                                                  const unsigned* __restrict__ prefwant,
                                                  unsigned* __restrict__ histg, int pass) {
    __shared__ unsigned lh[16][256];
    int b = blockIdx.x, blk = blockIdx.y, tid = threadIdx.x, wv = tid >> 6;
    for (int i = tid; i < 16 * 256; i += 1024) ((unsigned*)lh)[i] = 0u;
    __syncthreads();
    unsigned prefix = prefwant[2 * b];
    int shift = pass * 8;
    unsigned pmask = (pass == 3) ? 0u : (0xFFFFFFFFu << (shift + 8));
    const float* row = expr + (size_t)b * GG;
    int base = blk * 5120;
    #pragma unroll
    for (int j = 0; j < 5; ++j) {
        int g = base + j * 1024 + tid;
        if (g < GG) {
            unsigned key = to_key(row[g]);
            if ((key & pmask) == (prefix & pmask))
                atomicAdd(&lh[wv][(key >> shift) & 255u], 1u);
        }
    }
    __syncthreads();
    if (tid < 256) {
        unsigned s = 0;
        #pragma unroll
        for (int j = 0; j < 16; ++j) s += lh[j][tid];
        if (s) atomicAdd(&histg[b * 256 + tid], s);
    }
}

__global__ void topk_select(unsigned* __restrict__ prefwant,
                            unsigned* __restrict__ histg, int pass) {
    int b = blockIdx.x, lane = threadIdx.x;      // 64 threads
    int shift = pass * 8;
    unsigned pref = prefwant[2 * b];
    int want = (int)prefwant[2 * b + 1];
    unsigned cc[4];
    #pragma unroll
    for (int j = 0; j < 4; ++j) cc[j] = histg[b * 256 + lane * 4 + j];
    int s = (int)(cc[0] + cc[1] + cc[2] + cc[3]);
    int incl = s;
    #pragma unroll
    for (int o = 1; o < 64; o <<= 1) { int t = __shfl_up(incl, o); if (lane >= o) incl += t; }
    int total = __shfl(incl, 63);
    int a3 = total - incl;                        // count in bins above lane's top bin
    int a2 = a3 + (int)cc[3], a1 = a2 + (int)cc[2], a0 = a1 + (int)cc[1];
    int av[4] = {a0, a1, a2, a3};
    #pragma unroll
    for (int j = 0; j < 4; ++j) {
        if (av[j] < want && av[j] + (int)cc[j] >= want) {
            prefwant[2 * b] = pref | ((unsigned)(lane * 4 + j) << shift);
            prefwant[2 * b + 1] = (unsigned)(want - av[j]);
        }
    }
    #pragma unroll
    for (int j = 0; j < 4; ++j) histg[b * 256 + lane * 4 + j] = 0u;
}

__global__ __launch_bounds__(1024) void topk_c1(const float* __restrict__ expr,
                                                const unsigned* __restrict__ prefwant,
                                                int* __restrict__ blkcnt) {
    __shared__ int sred[16][2];
    int b = blockIdx.x, blk = blockIdx.y, tid = threadIdx.x;
    unsigned kth = prefwant[2 * b];
    const float* row = expr + (size_t)b * GG;
    int start = blk * 5120 + tid * 5;
    int eq = 0, gtp = 0;
    #pragma unroll
    for (int j = 0; j < 5; ++j) {
        int g = start + j;
        if (g < GG) {
            float e = row[g];
            unsigned key = to_key(e);
            eq += (key == kth);
            gtp += (key > kth && e > 0.0f);
        }
    }
    #pragma unroll
    for (int o = 1; o < 64; o <<= 1) { eq += __shfl_xor(eq, o); gtp += __shfl_xor(gtp, o); }
    if ((tid & 63) == 0) { sred[tid >> 6][0] = eq; sred[tid >> 6][1] = gtp; }
    __syncthreads();
    if (tid == 0) {
        int te = 0, tg = 0;
        #pragma unroll
        for (int i = 0; i < 16; ++i) { te += sred[i][0]; tg += sred[i][1]; }
        blkcnt[(b * TCH + blk) * 2] = te;
        blkcnt[(b * TCH + blk) * 2 + 1] = tg;
    }
}

__global__ void topk_c2(const unsigned* __restrict__ prefwant,
                        const int* __restrict__ blkcnt,
                        int* __restrict__ blkbase, int* __restrict__ cntout) {
    int b = blockIdx.x, lane = threadIdx.x;      // 64 threads
    int eq = 0, gtp = 0;
    if (lane < TCH) {
        eq = blkcnt[(b * TCH + lane) * 2];
        gtp = blkcnt[(b * TCH + lane) * 2 + 1];
    }
    int want = (int)prefwant[2 * b + 1];
    bool kthpos = prefwant[2 * b] > 0x80000000u;
    int incl = eq;
    #pragma unroll
    for (int o = 1; o < 8; o <<= 1) { int t = __shfl_up(incl, o); if (lane >= o) incl += t; }
    int eqb = incl - eq;
    int eqsel = kthpos ? min(max(want - eqb, 0), eq) : 0;
    int act = gtp + eqsel;
    int incl2 = act;
    #pragma unroll
    for (int o = 1; o < 8; o <<= 1) { int t = __shfl_up(incl2, o); if (lane >= o) incl2 += t; }
    int outb = incl2 - act;
    if (lane < TCH) {
        blkbase[(b * TCH + lane) * 2] = eqb;
        blkbase[(b * TCH + lane) * 2 + 1] = outb;
    }
    if (lane == TCH - 1) cntout[b] = incl2;
}

__global__ __launch_bounds__(1024) void topk_c3(const float* __restrict__ expr,
                                                const unsigned* __restrict__ prefwant,
                                                const int* __restrict__ blkbase,
                                                int* __restrict__ idxout) {
    __shared__ int shw[16];
    int b = blockIdx.x, blk = blockIdx.y, tid = threadIdx.x;
    unsigned kth = prefwant[2 * b];
    int want = (int)prefwant[2 * b + 1];
    const float* row = expr + (size_t)b * GG;
    int start = blk * 5120 + tid * 5;
    int eqt = 0;
    #pragma unroll
    for (int j = 0; j < 5; ++j) {
        int g = start + j;
        if (g < GG) eqt += (to_key(row[g]) == kth);
    }
    int eqbase = blkbase[(b * TCH + blk) * 2] + block_scan_excl_1024(eqt, shw);
    __syncthreads();
    int actt = 0;
    {
        int leq = 0;
        #pragma unroll
        for (int j = 0; j < 5; ++j) {
            int g = start + j;
            if (g < GG) {
                float e = row[g];
                unsigned key = to_key(e);
                bool sel = (key > kth) || (key == kth && (eqbase + leq) < want);
                leq += (key == kth);
                actt += (sel && e > 0.0f) ? 1 : 0;
            }
        }
    }
    int pos = blkbase[(b * TCH + blk) * 2 + 1] + block_scan_excl_1024(actt, shw);
    {
        int leq = 0;
        #pragma unroll
        for (int j = 0; j < 5; ++j) {
            int g = start + j;
            if (g < GG) {
                float e = row[g];
                unsigned key = to_key(e);
                bool sel = (key > kth) || (key == kth && (eqbase + leq) < want);
                leq += (key == kth);
                if (sel && e > 0.0f) idxout[b * KK + pos++] = g;
            }
        }
    }
}

// ---------------- weight fp32 -> bf16 ----------------
__global__ __launch_bounds__(256) void cvt_bf16_kernel(const float* __restrict__ s,
                                                       ub16* __restrict__ d, int n) {
    int i = blockIdx.x * 256 + threadIdx.x;
    if (i < n) d[i] = f2b(s[i]);
}

// ---------------- Token embedding ----------------
__global__ __launch_bounds__(256) void build_h_kernel(const float* __restrict__ expr,
                                                      const int* __restrict__ idxb,
                                                      const int* __restrict__ cntb,
                                                      const float* __restrict__ ep_w1,
                                                      const float* __restrict__ ep_b1,
                                                      ub16* __restrict__ H) {
    int i = blockIdx.x * 256 + threadIdx.x;       // < BB*KK*DD
    int r = i >> 8, d = i & 255;
    int b = r >> 11, jj = r & (KK - 1);
    float v = 0.0f;
    if (jj < cntb[b]) {
        int g = idxb[b * KK + jj];
        float e = expr[(size_t)b * GG + g];
        v = gelu_f(e * ep_w1[d] + ep_b1[d]);
    }
    H[i] = f2b(v);
}

__global__ __launch_bounds__(256) void assemble_kernel(const float* __restrict__ VAL,
                                                       const float* __restrict__ gene_emb,
                                                       const float* __restrict__ clsv,
                                                       const int* __restrict__ idxb,
                                                       const int* __restrict__ cntb,
                                                       float* __restrict__ x) {
    int i = blockIdx.x * 256 + threadIdx.x;       // < BT*DD
    int r = i >> 8, d = i & 255;
    int b = r / TT, t = r % TT;
    float v;
    if (t == 0) {
        v = clsv[d];
    } else {
        int jj = t - 1;
        if (jj < cntb[b]) {
            int g = idxb[b * KK + jj];
            v = gene_emb[(size_t)g * DD + d] + VAL[((size_t)b * KK + jj) * DD + d];
        } else {
            v = 0.0f;
        }
    }
    x[i] = v;
}

// ---------------- LayerNorm: wave per row, no barriers ----------------
__global__ __launch_bounds__(256) void ln_kernel(const float* __restrict__ X,
                                                 const float* __restrict__ s,
                                                 const float* __restrict__ bsh,
                                                 ub16* __restrict__ Y16,
                                                 float* __restrict__ Yf) {
    int w = threadIdx.x >> 6, lane = threadIdx.x & 63;
    size_t r = (size_t)blockIdx.x * 4 + w;        // BT = 4*2049 exactly
    float4 xv = *(const float4*)(X + r * 256 + lane * 4);
    float sum = xv.x + xv.y + xv.z + xv.w;
    #pragma unroll
    for (int o = 1; o < 64; o <<= 1) sum += __shfl_xor(sum, o);
    float mu = sum * (1.0f / 256.0f);
    float d0 = xv.x - mu, d1 = xv.y - mu, d2 = xv.z - mu, d3 = xv.w - mu;
    float vs = d0 * d0 + d1 * d1 + d2 * d2 + d3 * d3;
    #pragma unroll
    for (int o = 1; o < 64; o <<= 1) vs += __shfl_xor(vs, o);
    float rstd = rsqrtf(vs * (1.0f / 256.0f) + 1e-5f);
    float4 sc = *(const float4*)(s + lane * 4);
    float4 bc = *(const float4*)(bsh + lane * 4);
    float y0 = d0 * rstd * sc.x + bc.x;
    float y1 = d1 * rstd * sc.y + bc.y;
    float y2 = d2 * rstd * sc.z + bc.z;
    float y3 = d3 * rstd * sc.w + bc.w;
    if (Y16) {
        uint2 o2 = make_uint2(pk2(y0, y1), pk2(y2, y3));
        *(uint2*)(Y16 + r * 256 + lane * 4) = o2;
    } else {
        *(float4*)(Yf + r * 256 + lane * 4) = make_float4(y0, y1, y2, y3);
    }
}

// ---------------- bf16 MFMA NT-GEMM: C = act(A @ W^T + bias) (+R), 64x64 -------
__global__ __launch_bounds__(256) void gemm_bt16(const ub16* __restrict__ A,
                                                 const ub16* __restrict__ W,
                                                 const float* __restrict__ bias,
                                                 const float* __restrict__ R,
                                                 float* __restrict__ Cf,
                                                 ub16* __restrict__ Ch,
                                                 int M, int N, int K, int gelu_flag,
                                                 int qcols) {
    __shared__ ub16 As[2][64][40];
    __shared__ ub16 Ws[2][64][40];
    int tid = threadIdx.x;
    int lane = tid & 63, w = tid >> 6;
    int wr = (w >> 1) * 32, wc = (w & 1) * 32;
    int bm = blockIdx.y * 64, bn = blockIdx.x * 64;
    f32x4 acc[2][2] = {};

    int lrow = tid >> 2, lc8 = (tid & 3) * 8;
    int arow = min(bm + lrow, M - 1);
    const ub16* ap = A + (size_t)arow * K + lc8;
    const ub16* wp = W + (size_t)(bn + lrow) * K + lc8;

    int fr = lane & 15, fc = 8 * (lane >> 4);
    for (int k0 = 0; k0 < K; k0 += 64) {
        bf16x8 av0 = *(const bf16x8*)(ap + k0);
        bf16x8 av1 = *(const bf16x8*)(ap + k0 + 32);
        bf16x8 wv0 = *(const bf16x8*)(wp + k0);
        bf16x8 wv1 = *(const bf16x8*)(wp + k0 + 32);
        *(bf16x8*)&As[0][lrow][lc8] = av0;
        *(bf16x8*)&As[1][lrow][lc8] = av1;
        *(bf16x8*)&Ws[0][lrow][lc8] = wv0;
        *(bf16x8*)&Ws[1][lrow][lc8] = wv1;
        __syncthreads();
        #pragma unroll
        for (int ks = 0; ks < 2; ++ks) {
            bf16x8 a0 = *(const bf16x8*)&As[ks][wr + fr][fc];
            bf16x8 a1 = *(const bf16x8*)&As[ks][wr + 16 + fr][fc];
            bf16x8 b0 = *(const bf16x8*)&Ws[ks][wc + fr][fc];
            bf16x8 b1 = *(const bf16x8*)&Ws[ks][wc + 16 + fr][fc];
            acc[0][0] = __builtin_amdgcn_mfma_f32_16x16x32_bf16(a0, b0, acc[0][0], 0, 0, 0);
            acc[0][1] = __builtin_amdgcn_mfma_f32_16x16x32_bf16(a0, b1, acc[0][1], 0, 0, 0);
            acc[1][0] = __builtin_amdgcn_mfma_f32_16x16x32_bf16(a1, b0, acc[1][0], 0, 0, 0);
            acc[1][1] = __builtin_amdgcn_mfma_f32_16x16x32_bf16(a1, b1, acc[1][1], 0, 0, 0);
        }
        __syncthreads();
    }

    #pragma unroll
    for (int i = 0; i < 2; ++i) {
        #pragma unroll
        for (int j = 0; j < 2; ++j) {
            #pragma unroll
            for (int reg = 0; reg < 4; ++reg) {
                int gm = bm + wr + i * 16 + (lane >> 4) * 4 + reg;
                int gn = bn + wc + j * 16 + (lane & 15);
                if (gm >= M) continue;
                float v = acc[i][j][reg] + bias[gn];
                if (R) v += R[(size_t)gm * N + gn];
                if (gelu_flag) v = gelu_f(v);
                if (gn < qcols) v *= QSC;
                if (Cf) Cf[(size_t)gm * N + gn] = v;
                else    Ch[(size_t)gm * N + gn] = f2b(v);
            }
        }
    }
}

// ---------------- bf16 MFMA NT-GEMM, 64x128 tile (for N>=128 multiples) --------
__global__ __launch_bounds__(256) void gemm_bn128(const ub16* __restrict__ A,
                                                  const ub16* __restrict__ W,
                                                  const float* __restrict__ bias,
                                                  ub16* __restrict__ Ch,
                                                  int M, int N, int K, int gelu_flag,
                                                  int qcols) {
    __shared__ ub16 As[2][64][40];
    __shared__ ub16 Ws[2][128][40];
    int tid = threadIdx.x, lane = tid & 63, w = tid >> 6;
    int wr = (w >> 1) * 32, wc = (w & 1) * 64;
    int bm = blockIdx.y * 64, bn = blockIdx.x * 128;
    f32x4 acc[2][4] = {};

    int arow = tid >> 2, aseg = tid & 3, aks = aseg >> 1, aoff = (aseg & 1) * 16;
    const ub16* apg = A + (size_t)min(bm + arow, M - 1) * K + aseg * 16;
    int wrow = tid >> 1, wks = tid & 1;
    const ub16* wpg = W + (size_t)(bn + wrow) * K + wks * 32;
    int fr = lane & 15, fc = 8 * (lane >> 4);

    bf16x8 ra0 = *(const bf16x8*)apg;
    bf16x8 ra1 = *(const bf16x8*)(apg + 8);
    bf16x8 rb0 = *(const bf16x8*)wpg;
    bf16x8 rb1 = *(const bf16x8*)(wpg + 8);
    bf16x8 rb2 = *(const bf16x8*)(wpg + 16);
    bf16x8 rb3 = *(const bf16x8*)(wpg + 24);

    for (int k0 = 0; k0 < K; k0 += 64) {
        *(bf16x8*)&As[aks][arow][aoff] = ra0;
        *(bf16x8*)&As[aks][arow][aoff + 8] = ra1;
        *(bf16x8*)&Ws[wks][wrow][0]  = rb0;
        *(bf16x8*)&Ws[wks][wrow][8]  = rb1;
        *(bf16x8*)&Ws[wks][wrow][16] = rb2;
        *(bf16x8*)&Ws[wks][wrow][24] = rb3;
        __syncthreads();
        if (k0 + 64 < K) {
            ra0 = *(const bf16x8*)(apg + k0 + 64);
            ra1 = *(const bf16x8*)(apg + k0 + 72);
            rb0 = *(const bf16x8*)(wpg + k0 + 64);
            rb1 = *(const bf16x8*)(wpg + k0 + 72);
            rb2 = *(const bf16x8*)(wpg + k0 + 80);
            rb3 = *(const bf16x8*)(wpg + k0 + 88);
        }
        #pragma unroll
        for (int ks = 0; ks < 2; ++ks) {
            bf16x8 af[2], bfv[4];
            #pragma unroll
            for (int mr = 0; mr < 2; ++mr)
                af[mr] = *(const bf16x8*)&As[ks][wr + mr * 16 + fr][fc];
            #pragma unroll
            for (int nr = 0; nr < 4; ++nr)
                bfv[nr] = *(const bf16x8*)&Ws[ks][wc + nr * 16 + fr][fc];
            #pragma unroll
            for (int mr = 0; mr < 2; ++mr)
                #pragma unroll
                for (int nr = 0; nr < 4; ++nr)
                    acc[mr][nr] = __builtin_amdgcn_mfma_f32_16x16x32_bf16(
                        af[mr], bfv[nr], acc[mr][nr], 0, 0, 0);
        }
        __syncthreads();
    }

    #pragma unroll
    for (int mr = 0; mr < 2; ++mr) {
        #pragma unroll
        for (int nr = 0; nr < 4; ++nr) {
            #pragma unroll
            for (int reg = 0; reg < 4; ++reg) {
                int gm = bm + wr + mr * 16 + (lane >> 4) * 4 + reg;
                int gn = bn + wc + nr * 16 + (lane & 15);
                if (gm >= M) continue;
                float v = acc[mr][nr][reg] + bias[gn];
                if (gelu_flag) v = gelu_f(v);
                if (gn < qcols) v *= QSC;
                Ch[(size_t)gm * N + gn] = f2b(v);
            }
        }
    }
}

// ---------------- K/V cache prep: dense tiled Kc + k-permuted transposed Vt ----
__global__ __launch_bounds__(256) void kvprep(const ub16* __restrict__ qkv,
                                              ub16* __restrict__ Kc,
                                              ub16* __restrict__ Vt) {
    __shared__ unsigned vl[32][33];
    int bh = blockIdx.x, b = bh >> 3, h = bh & 7;
    int c = blockIdx.y;                 // 64-key chunk
    int tid = threadIdx.x;
    int krel = tid >> 2;                // 0..63
    int key = c * 64 + krel;
    int d8 = (tid & 3) * 8;
    U4B kv = {}, vv = {};
    if (key < TT) {
        const ub16* p = qkv + ((size_t)(b * TT + key)) * 768 + 256 + h * 32 + d8;
        kv.v = *(const bf16x8*)p;
        vv.v = *(const bf16x8*)(p + 256);
    }
    int kt = c * 2 + (krel >> 5);
    if (kt < NT)
        *(bf16x8*)(Kc + (((size_t)bh * NT + kt) * 32 + (krel & 31)) * 32 + d8) = kv.v;

    unsigned pu[4];
    #pragma unroll
    for (int j = 0; j < 4; ++j) pu[j] = __shfl_xor(vv.u[j], 4);
    if (!(krel & 1)) {
        int kp = krel >> 1;
        #pragma unroll
        for (int j = 0; j < 8; ++j) {
            unsigned mine = (vv.u[j >> 1] >> ((j & 1) * 16)) & 0xffffu;
            unsigned oth  = (pu[j >> 1] >> ((j & 1) * 16)) & 0xffffu;
            vl[d8 + j][kp] = mine | (oth << 16);
        }
    }
    __syncthreads();
    int d = tid >> 3, c8 = tid & 7;
    int kt2 = c * 2 + (c8 >> 2);
    if (kt2 < NT) {
        unsigned* vdst = (unsigned*)(Vt + (((size_t)bh * NT + kt2) * 32 + d) * 32);
        #pragma unroll
        for (int ih = 0; ih < 2; ++ih) {
            int pkr = (c8 & 3) * 4 + ih * 2;     // key-pair index 0..15 (even)
            int dp = (pkr & 1) | ((pkr & 2) << 1) | ((pkr & 4) >> 1) | (pkr & 8);
            uint2 o2 = make_uint2(vl[d][c8 * 4 + ih * 2], vl[d][c8 * 4 + ih * 2 + 1]);
            *(uint2*)(vdst + dp) = o2;
        }
    }
}

// ---------------- MFMA flash attention: split-K + 2-tile ILP -----------------
// grid (B*H, 65); 4 waves share one 32-query tile, each wave every-4th k-tile,
// processing PAIRS of tiles with independent accumulators (ot0/ot1, l0/l1).
__global__ __launch_bounds__(256) void attn_mfma5(const ub16* __restrict__ qkv,
                                                  const ub16* __restrict__ Kc,
                                                  const ub16* __restrict__ Vt,
                                                  const int* __restrict__ cnt,
                                                  ub16* __restrict__ attno) {
    __shared__ float Olds[4][32][33];
    __shared__ float Oll[4][32];
    int bh = blockIdx.x, b = bh >> 3, h = bh & 7;
    int tid = threadIdx.x;
    int w = tid >> 6, lane = tid & 63, hi = lane >> 5, q = lane & 31;
    int qt = blockIdx.y;
    int t = qt * 32 + q;
    int nvalid = cnt[b] + 1;
    int nkt = (nvalid + 31) >> 5;
    int nfull = (nvalid & 31) ? nkt - 1 : nkt;

    int tc = min(t, TT - 1);
    const ub16* qp = qkv + ((size_t)(b * TT + tc)) * 768 + h * 32 + 8 * hi;
    bf16x8 bq0 = *(const bf16x8*)qp;        // Q pre-scaled by QSC in gemm epilogue
    bf16x8 bq1 = *(const bf16x8*)(qp + 16);

    const ub16* kbase = Kc + (size_t)bh * NT * 1024 + q * 32 + 8 * hi;
    const ub16* vbase = Vt + (size_t)bh * NT * 1024 + q * 32 + 8 * hi;

    f32x16 ot0 = {}, ot1 = {};
    float l0 = 0.0f, l1 = 0.0f;

    // preload pair (w, w+4), clamped into the zero-padded NT-tile caches
    size_t oA = (size_t)min(w, NT - 1) * 1024, oB = (size_t)min(w + 4, NT - 1) * 1024;
    bf16x8 kA0 = *(const bf16x8*)(kbase + oA);
    bf16x8 kA1 = *(const bf16x8*)(kbase + oA + 16);
    bf16x8 vA0 = *(const bf16x8*)(vbase + oA);
    bf16x8 vA1 = *(const bf16x8*)(vbase + oA + 16);
    bf16x8 kB0 = *(const bf16x8*)(kbase + oB);
    bf16x8 kB1 = *(const bf16x8*)(kbase + oB + 16);
    bf16x8 vB0 = *(const bf16x8*)(vbase + oB);
    bf16x8 vB1 = *(const bf16x8*)(vbase + oB + 16);

    for (int kt = w; kt < nkt; kt += 8) {
        // prefetch next pair (clamped)
        size_t nA = (size_t)min(kt + 8, NT - 1) * 1024;
        size_t nB = (size_t)min(kt + 12, NT - 1) * 1024;
        bf16x8 nkA0 = *(const bf16x8*)(kbase + nA);
        bf16x8 nkA1 = *(const bf16x8*)(kbase + nA + 16);
        bf16x8 nvA0 = *(const bf16x8*)(vbase + nA);
        bf16x8 nvA1 = *(const bf16x8*)(vbase + nA + 16);
        bf16x8 nkB0 = *(const bf16x8*)(kbase + nB);
        bf16x8 nkB1 = *(const bf16x8*)(kbase + nB + 16);
        bf16x8 nvB0 = *(const bf16x8*)(vbase + nB);
        bf16x8 nvB1 = *(const bf16x8*)(vbase + nB + 16);

        f32x16 z = {};
        f32x16 stA = __builtin_amdgcn_mfma_f32_32x32x16_bf16(kA0, bq0, z, 0, 0, 0);
        stA = __builtin_amdgcn_mfma_f32_32x32x16_bf16(kA1, bq1, stA, 0, 0, 0);
        f32x16 stB = __builtin_amdgcn_mfma_f32_32x32x16_bf16(kB0, bq0, z, 0, 0, 0);
        stB = __builtin_amdgcn_mfma_f32_32x32x16_bf16(kB1, bq1, stB, 0, 0, 0);

        if (kt >= nfull) {                      // rare: partial tile A
            int lim = nvalid - (kt << 5);
            #pragma unroll
            for (int r = 0; r < 16; ++r) {
                int off = (r & 3) + 8 * (r >> 2) + 4 * hi;
                if (off >= lim) stA[r] = -1e30f;
            }
        }
        if (kt + 4 >= nfull) {                  // rare: partial OR absent tile B
            int lim = nvalid - ((kt + 4) << 5);
            #pragma unroll
            for (int r = 0; r < 16; ++r) {
                int off = (r & 3) + 8 * (r >> 2) + 4 * hi;
                if (off >= lim) stB[r] = -1e30f;
            }
        }

        float tsA = 0.0f, tsB = 0.0f;
        #pragma unroll
        for (int r = 0; r < 16; ++r) { float p = exp2f(stA[r]); stA[r] = p; tsA += p; }
        #pragma unroll
        for (int r = 0; r < 16; ++r) { float p = exp2f(stB[r]); stB[r] = p; tsB += p; }
        l0 += tsA; l1 += tsB;

        U4B pA0, pA1, pB0, pB1;
        #pragma unroll
        for (int jj = 0; jj < 4; ++jj) {
            pA0.u[jj] = pk2(stA[2 * jj], stA[2 * jj + 1]);
            pA1.u[jj] = pk2(stA[8 + 2 * jj], stA[9 + 2 * jj]);
            pB0.u[jj] = pk2(stB[2 * jj], stB[2 * jj + 1]);
            pB1.u[jj] = pk2(stB[8 + 2 * jj], stB[9 + 2 * jj]);
        }
        ot0 = __builtin_amdgcn_mfma_f32_32x32x16_bf16(vA0, pA0.v, ot0, 0, 0, 0);
        ot0 = __builtin_amdgcn_mfma_f32_32x32x16_bf16(vA1, pA1.v, ot0, 0, 0, 0);
        ot1 = __builtin_amdgcn_mfma_f32_32x32x16_bf16(vB0, pB0.v, ot1, 0, 0, 0);
        ot1 = __builtin_amdgcn_mfma_f32_32x32x16_bf16(vB1, pB1.v, ot1, 0, 0, 0);

        kA0 = nkA0; kA1 = nkA1; vA0 = nvA0; vA1 = nvA1;
        kB0 = nkB0; kB1 = nkB1; vB0 = nvB0; vB1 = nvB1;
    }

    float l = l0 + l1;
    l += __shfl_xor(l, 32);
    #pragma unroll
    for (int r = 0; r < 16; ++r) {
        int d = (r & 3) + 8 * (r >> 2) + 4 * hi;
        Olds[w][q][d] = ot0[r] + ot1[r];
    }
    if (hi == 0) Oll[w][q] = l;
    __syncthreads();

    // merge: thread -> (q row, 4-wide d group); plain sums (shared fixed m)
    int qq = tid >> 3, dg = tid & 7;
    int trow = qt * 32 + qq;
    if (trow < TT) {
        float L = Oll[0][qq] + Oll[1][qq] + Oll[2][qq] + Oll[3][qq];
        float rL = 1.0f / L;
        float o[4];
        #pragma unroll
        for (int j = 0; j < 4; ++j) {
            int d = dg * 4 + j;
            o[j] = (Olds[0][qq][d] + Olds[1][qq][d] +
                    Olds[2][qq][d] + Olds[3][qq][d]) * rL;
        }
        uint2 o2 = make_uint2(pk2(o[0], o[1]), pk2(o[2], o[3]));
        *(uint2*)(attno + ((size_t)(b * TT + trow)) * 256 + h * 32 + dg * 4) = o2;
    }
}

// ---------------- head ----------------
__global__ __launch_bounds__(512) void head_kernel(const float* __restrict__ Y,
                                                   const float* __restrict__ w1,
                                                   const float* __restrict__ b1,
                                                   const float* __restrict__ w2,
                                                   const float* __restrict__ b2,
                                                   float* __restrict__ out) {
    __shared__ float clsr[256];
    __shared__ float t1[512];
    int b = blockIdx.x, tid = threadIdx.x;
    if (tid < 256) clsr[tid] = Y[((size_t)b * TT) * DD + tid];
    __syncthreads();
    float acc = b1[tid];
    const float* w = w1 + (size_t)tid * 256;
    for (int k = 0; k < 256; ++k) acc += clsr[k] * w[k];
    t1[tid] = gelu_f(acc);
    __syncthreads();
    float acc2 = b2[tid];
    const float* wr = w2 + (size_t)tid * 512;
    for (int k = 0; k < 512; ++k) acc2 += t1[k] * wr[k];
    out[(size_t)b * 512 + tid] = acc2;
}

// ---------------- launch ----------------
extern "C" void kernel_launch(void* const* d_in, const int* in_sizes, int n_in,
                              void* d_out, int out_size, void* d_ws, size_t ws_size,
                              hipStream_t stream) {
    (void)in_sizes; (void)n_in; (void)out_size; (void)ws_size;
    const float* expr     = (const float*)d_in[0];
    const float* gene_emb = (const float*)d_in[1];
    const float* ep_w1    = (const float*)d_in[2];
    const float* ep_b1    = (const float*)d_in[3];
    const float* ep_w2    = (const float*)d_in[4];
    const float* ep_b2    = (const float*)d_in[5];
    const float* clsv     = (const float*)d_in[6];
    const float* ln1_s    = (const float*)d_in[7];
    const float* ln1_b    = (const float*)d_in[8];
    const float* qkv_w    = (const float*)d_in[9];
    const float* qkv_b    = (const float*)d_in[10];
    const float* out_w    = (const float*)d_in[11];
    const float* out_b    = (const float*)d_in[12];
    const float* ln2_s    = (const float*)d_in[13];
    const float* ln2_b    = (const float*)d_in[14];
    const float* ff_w1    = (const float*)d_in[15];
    const float* ff_b1    = (const float*)d_in[16];
    const float* ff_w2    = (const float*)d_in[17];
    const float* ff_b2    = (const float*)d_in[18];
    const float* fn_s     = (const float*)d_in[19];
    const float* fn_b     = (const float*)d_in[20];
    const float* pr_w1    = (const float*)d_in[21];
    const float* pr_b1    = (const float*)d_in[22];
    const float* pr_w2    = (const float*)d_in[23];
    const float* pr_b2    = (const float*)d_in[24];
    float* outp = (float*)d_out;

    const size_t KVSZ = (size_t)32 * NT * 1024;

    // workspace layout
    float* x   = (float*)d_ws;                       // BT*256 f32
    float* VAL = x + (size_t)BT * 256;               // 8192*256 f32; reused as Vt + final-LN out
    ub16* y16   = (ub16*)(VAL + (size_t)8192 * 256);
    ub16* qkv16 = y16 + (size_t)BT * 256;
    ub16* att16 = qkv16 + (size_t)BT * 768;
    ub16* ff116 = att16 + (size_t)BT * 256;
    ub16* kc_h  = ff116 + (size_t)BT * 1024;
    ub16* wqkv  = kc_h + KVSZ;
    ub16* wout  = wqkv + (size_t)LL * 768 * 256;
    ub16* wff1  = wout + (size_t)LL * 256 * 256;
    ub16* wff2  = wff1 + (size_t)LL * 1024 * 256;
    ub16* wep2  = wff2 + (size_t)LL * 256 * 1024;
    int*  idxb  = (int*)(wep2 + (size_t)256 * 256);
    int*  cntb  = idxb + BB * KK;
    unsigned* prefwant = (unsigned*)(cntb + BB);
    unsigned* histg    = prefwant + BB * 2;
    int* blkcnt  = (int*)(histg + BB * 256);
    int* blkbase = blkcnt + BB * TCH * 2;
    ub16* H16 = kc_h;
    ub16* Kc  = kc_h;
    ub16* Vt  = (ub16*)VAL;

    // 1) top-K (multi-block radix select)
    topk_init<<<1, 1024, 0, stream>>>(prefwant, histg);
    for (int p = 3; p >= 0; --p) {
        topk_hist<<<dim3(BB, TCH), 1024, 0, stream>>>(expr, prefwant, histg, p);
        topk_select<<<BB, 64, 0, stream>>>(prefwant, histg, p);
    }
    topk_c1<<<dim3(BB, TCH), 1024, 0, stream>>>(expr, prefwant, blkcnt);
    topk_c2<<<BB, 64, 0, stream>>>(prefwant, blkcnt, blkbase, cntb);
    topk_c3<<<dim3(BB, TCH), 1024, 0, stream>>>(expr, prefwant, blkbase, idxb);

    // 2) weights -> bf16
    cvt_bf16_kernel<<<(LL*768*256 + 255)/256, 256, 0, stream>>>(qkv_w, wqkv, LL*768*256);
    cvt_bf16_kernel<<<(LL*256*256 + 255)/256, 256, 0, stream>>>(out_w, wout, LL*256*256);
    cvt_bf16_kernel<<<(LL*1024*256 + 255)/256, 256, 0, stream>>>(ff_w1, wff1, LL*1024*256);
    cvt_bf16_kernel<<<(LL*256*1024 + 255)/256, 256, 0, stream>>>(ff_w2, wff2, LL*256*1024);
    cvt_bf16_kernel<<<(256*256 + 255)/256, 256, 0, stream>>>(ep_w2, wep2, 256*256);

    // 3) token embeddings
    build_h_kernel<<<(BB * KK * DD) / 256, 256, 0, stream>>>(expr, idxb, cntb, ep_w1, ep_b1, H16);
    gemm_bt16<<<dim3(4, 128), 256, 0, stream>>>(H16, wep2, ep_b2, nullptr, VAL, nullptr,
                                                8192, 256, 256, 0, 0);
    assemble_kernel<<<BT, 256, 0, stream>>>(VAL, gene_emb, clsv, idxb, cntb, x);

    // 4) transformer layers
    for (int i = 0; i < LL; ++i) {
        ln_kernel<<<BT / 4, 256, 0, stream>>>(x, ln1_s + i * DD, ln1_b + i * DD, y16, nullptr);
        gemm_bn128<<<dim3(6, 129), 256, 0, stream>>>(y16, wqkv + (size_t)i * 768 * 256,
                                                     qkv_b + i * 768, qkv16,
                                                     BT, 768, 256, 0, 256);
        kvprep<<<dim3(BB * HH, 33), 256, 0, stream>>>(qkv16, Kc, Vt);
        attn_mfma5<<<dim3(BB * HH, NT), 256, 0, stream>>>(qkv16, Kc, Vt, cntb, att16);
        gemm_bt16<<<dim3(4, 129), 256, 0, stream>>>(att16, wout + (size_t)i * 256 * 256,
                                                    out_b + i * 256, x, x, nullptr,
                                                    BT, 256, 256, 0, 0);
        ln_kernel<<<BT / 4, 256, 0, stream>>>(x, ln2_s + i * DD, ln2_b + i * DD, y16, nullptr);
        gemm_bn128<<<dim3(8, 129), 256, 0, stream>>>(y16, wff1 + (size_t)i * 1024 * 256,
                                                     ff_b1 + i * 1024, ff116,
                                                     BT, 1024, 256, 1, 0);
        gemm_bt16<<<dim3(4, 129), 256, 0, stream>>>(ff116, wff2 + (size_t)i * 256 * 1024,
                                                    ff_b2 + i * 256, x, x, nullptr,
                                                    BT, 256, 1024, 0, 0);
    }

    // 5) final LN + head
    ln_kernel<<<BT / 4, 256, 0, stream>>>(x, fn_s, fn_b, nullptr, VAL);
    head_kernel<<<BB, 512, 0, stream>>>(VAL, pr_w1, pr_b1, pr_w2, pr_b2, outp);
}

// Round 9
// 871.365 us; speedup vs baseline: 1.1865x; 1.1865x over previous
//
#include <hip/hip_runtime.h>
#include <hip/hip_bf16.h>
#include <math.h>

// Problem constants
#define GG 33538
#define DD 256
#define LL 6
#define HH 8
#define KK 2048
#define BB 4
#define TT 2049          // K+1 tokens
#define BT (BB*TT)       // 8196
#define NT 65            // 32-key tiles per (b,h)
#define TCH 7            // topk blocks per batch row (7*5120 >= GG)
#define QSC (0.17677669529663688f * 1.44269504088896340f)   // 1/sqrt(32) * log2e

#if __has_builtin(__builtin_amdgcn_exp2f)
#define EXP2(x) __builtin_amdgcn_exp2f(x)
#else
#define EXP2(x) exp2f(x)
#endif

typedef __bf16 bf16x8 __attribute__((ext_vector_type(8)));
typedef float f32x4 __attribute__((ext_vector_type(4)));
typedef float f32x16 __attribute__((ext_vector_type(16)));
typedef unsigned short ub16;

union BW { __bf16 h; ub16 u; };
__device__ __forceinline__ ub16 f2b(float x) { BW w; w.h = (__bf16)x; return w.u; }
__device__ __forceinline__ unsigned pk2(float a, float b) {
    return (unsigned)f2b(a) | ((unsigned)f2b(b) << 16);
}
union U4B { unsigned u[4]; bf16x8 v; };

__device__ __forceinline__ float gelu_f(float x) {
    return 0.5f * x * (1.0f + erff(x * 0.70710678118654752440f));
}

__device__ __forceinline__ unsigned to_key(float x) {
    unsigned u = __float_as_uint(x);
    return (u & 0x80000000u) ? ~u : (u | 0x80000000u);
}

// ---------------- Top-K phase kernels (multi-block radix select) ----------------
__device__ int block_scan_excl_1024(int v, int* shw) {
    int lane = threadIdx.x & 63, w = threadIdx.x >> 6;
    int x = v;
    #pragma unroll
    for (int o = 1; o < 64; o <<= 1) {
        int t = __shfl_up(x, o, 64);
        if (lane >= o) x += t;
    }
    if (lane == 63) shw[w] = x;
    __syncthreads();
    if (w == 0) {
        int y = (lane < 16) ? shw[lane] : 0;
        #pragma unroll
        for (int o = 1; o < 16; o <<= 1) {
            int t = __shfl_up(y, o, 64);
            if (lane >= o) y += t;
        }
        if (lane < 16) shw[lane] = y;
    }
    __syncthreads();
    int off = (w == 0) ? 0 : shw[w - 1];
    return off + x - v;   // exclusive prefix
}

__global__ void topk_init(unsigned* __restrict__ prefwant, unsigned* __restrict__ histg) {
    int i = threadIdx.x;
    if (i < BB * 256) histg[i] = 0u;
    if (i < BB) { prefwant[2 * i] = 0u; prefwant[2 * i + 1] = KK; }
}

__global__ __launch_bounds__(1024) void topk_hist(const float* __restrict__ expr,
                                                  const unsigned* __restrict__ prefwant,
                                                  unsigned* __restrict__ histg, int pass) {
    __shared__ unsigned lh[16][256];
    int b = blockIdx.x, blk = blockIdx.y, tid = threadIdx.x, wv = tid >> 6;
    for (int i = tid; i < 16 * 256; i += 1024) ((unsigned*)lh)[i] = 0u;
    __syncthreads();
    unsigned prefix = prefwant[2 * b];
    int shift = pass * 8;
    unsigned pmask = (pass == 3) ? 0u : (0xFFFFFFFFu << (shift + 8));
    const float* row = expr + (size_t)b * GG;
    int base = blk * 5120;
    #pragma unroll
    for (int j = 0; j < 5; ++j) {
        int g = base + j * 1024 + tid;
        if (g < GG) {
            unsigned key = to_key(row[g]);
            if ((key & pmask) == (prefix & pmask))
                atomicAdd(&lh[wv][(key >> shift) & 255u], 1u);
        }
    }
    __syncthreads();
    if (tid < 256) {
        unsigned s = 0;
        #pragma unroll
        for (int j = 0; j < 16; ++j) s += lh[j][tid];
        if (s) atomicAdd(&histg[b * 256 + tid], s);
    }
}

__global__ void topk_select(unsigned* __restrict__ prefwant,
                            unsigned* __restrict__ histg, int pass) {
    int b = blockIdx.x, lane = threadIdx.x;      // 64 threads
    int shift = pass * 8;
    unsigned pref = prefwant[2 * b];
    int want = (int)prefwant[2 * b + 1];
    unsigned cc[4];
    #pragma unroll
    for (int j = 0; j < 4; ++j) cc[j] = histg[b * 256 + lane * 4 + j];
    int s = (int)(cc[0] + cc[1] + cc[2] + cc[3]);
    int incl = s;
    #pragma unroll
    for (int o = 1; o < 64; o <<= 1) { int t = __shfl_up(incl, o); if (lane >= o) incl += t; }
    int total = __shfl(incl, 63);
    int a3 = total - incl;                        // count in bins above lane's top bin
    int a2 = a3 + (int)cc[3], a1 = a2 + (int)cc[2], a0 = a1 + (int)cc[1];
    int av[4] = {a0, a1, a2, a3};
    #pragma unroll
    for (int j = 0; j < 4; ++j) {
        if (av[j] < want && av[j] + (int)cc[j] >= want) {
            prefwant[2 * b] = pref | ((unsigned)(lane * 4 + j) << shift);
            prefwant[2 * b + 1] = (unsigned)(want - av[j]);
        }
    }
    #pragma unroll
    for (int j = 0; j < 4; ++j) histg[b * 256 + lane * 4 + j] = 0u;
}

__global__ __launch_bounds__(1024) void topk_c1(const float* __restrict__ expr,
                                                const unsigned* __restrict__ prefwant,
                                                int* __restrict__ blkcnt) {
    __shared__ int sred[16][2];
    int b = blockIdx.x, blk = blockIdx.y, tid = threadIdx.x;
    unsigned kth = prefwant[2 * b];
    const float* row = expr + (size_t)b * GG;
    int start = blk * 5120 + tid * 5;
    int eq = 0, gtp = 0;
    #pragma unroll
    for (int j = 0; j < 5; ++j) {
        int g = start + j;
        if (g < GG) {
            float e = row[g];
            unsigned key = to_key(e);
            eq += (key == kth);
            gtp += (key > kth && e > 0.0f);
        }
    }
    #pragma unroll
    for (int o = 1; o < 64; o <<= 1) { eq += __shfl_xor(eq, o); gtp += __shfl_xor(gtp, o); }
    if ((tid & 63) == 0) { sred[tid >> 6][0] = eq; sred[tid >> 6][1] = gtp; }
    __syncthreads();
    if (tid == 0) {
        int te = 0, tg = 0;
        #pragma unroll
        for (int i = 0; i < 16; ++i) { te += sred[i][0]; tg += sred[i][1]; }
        blkcnt[(b * TCH + blk) * 2] = te;
        blkcnt[(b * TCH + blk) * 2 + 1] = tg;
    }
}

__global__ void topk_c2(const unsigned* __restrict__ prefwant,
                        const int* __restrict__ blkcnt,
                        int* __restrict__ blkbase, int* __restrict__ cntout) {
    int b = blockIdx.x, lane = threadIdx.x;      // 64 threads
    int eq = 0, gtp = 0;
    if (lane < TCH) {
        eq = blkcnt[(b * TCH + lane) * 2];
        gtp = blkcnt[(b * TCH + lane) * 2 + 1];
    }
    int want = (int)prefwant[2 * b + 1];
    bool kthpos = prefwant[2 * b] > 0x80000000u;
    int incl = eq;
    #pragma unroll
    for (int o = 1; o < 8; o <<= 1) { int t = __shfl_up(incl, o); if (lane >= o) incl += t; }
    int eqb = incl - eq;
    int eqsel = kthpos ? min(max(want - eqb, 0), eq) : 0;
    int act = gtp + eqsel;
    int incl2 = act;
    #pragma unroll
    for (int o = 1; o < 8; o <<= 1) { int t = __shfl_up(incl2, o); if (lane >= o) incl2 += t; }
    int outb = incl2 - act;
    if (lane < TCH) {
        blkbase[(b * TCH + lane) * 2] = eqb;
        blkbase[(b * TCH + lane) * 2 + 1] = outb;
    }
    if (lane == TCH - 1) cntout[b] = incl2;
}

__global__ __launch_bounds__(1024) void topk_c3(const float* __restrict__ expr,
                                                const unsigned* __restrict__ prefwant,
                                                const int* __restrict__ blkbase,
                                                int* __restrict__ idxout) {
    __shared__ int shw[16];
    int b = blockIdx.x, blk = blockIdx.y, tid = threadIdx.x;
    unsigned kth = prefwant[2 * b];
    int want = (int)prefwant[2 * b + 1];
    const float* row = expr + (size_t)b * GG;
    int start = blk * 5120 + tid * 5;
    int eqt = 0;
    #pragma unroll
    for (int j = 0; j < 5; ++j) {
        int g = start + j;
        if (g < GG) eqt += (to_key(row[g]) == kth);
    }
    int eqbase = blkbase[(b * TCH + blk) * 2] + block_scan_excl_1024(eqt, shw);
    __syncthreads();
    int actt = 0;
    {
        int leq = 0;
        #pragma unroll
        for (int j = 0; j < 5; ++j) {
            int g = start + j;
            if (g < GG) {
                float e = row[g];
                unsigned key = to_key(e);
                bool sel = (key > kth) || (key == kth && (eqbase + leq) < want);
                leq += (key == kth);
                actt += (sel && e > 0.0f) ? 1 : 0;
            }
        }
    }
    int pos = blkbase[(b * TCH + blk) * 2 + 1] + block_scan_excl_1024(actt, shw);
    {
        int leq = 0;
        #pragma unroll
        for (int j = 0; j < 5; ++j) {
            int g = start + j;
            if (g < GG) {
                float e = row[g];
                unsigned key = to_key(e);
                bool sel = (key > kth) || (key == kth && (eqbase + leq) < want);
                leq += (key == kth);
                if (sel && e > 0.0f) idxout[b * KK + pos++] = g;
            }
        }
    }
}

// ---------------- weight fp32 -> bf16 ----------------
__global__ __launch_bounds__(256) void cvt_bf16_kernel(const float* __restrict__ s,
                                                       ub16* __restrict__ d, int n) {
    int i = blockIdx.x * 256 + threadIdx.x;
    if (i < n) d[i] = f2b(s[i]);
}

// ---------------- Token embedding ----------------
__global__ __launch_bounds__(256) void build_h_kernel(const float* __restrict__ expr,
                                                      const int* __restrict__ idxb,
                                                      const int* __restrict__ cntb,
                                                      const float* __restrict__ ep_w1,
                                                      const float* __restrict__ ep_b1,
                                                      ub16* __restrict__ H) {
    int i = blockIdx.x * 256 + threadIdx.x;       // < BB*KK*DD
    int r = i >> 8, d = i & 255;
    int b = r >> 11, jj = r & (KK - 1);
    float v = 0.0f;
    if (jj < cntb[b]) {
        int g = idxb[b * KK + jj];
        float e = expr[(size_t)b * GG + g];
        v = gelu_f(e * ep_w1[d] + ep_b1[d]);
    }
    H[i] = f2b(v);
}

__global__ __launch_bounds__(256) void assemble_kernel(const float* __restrict__ VAL,
                                                       const float* __restrict__ gene_emb,
                                                       const float* __restrict__ clsv,
                                                       const int* __restrict__ idxb,
                                                       const int* __restrict__ cntb,
                                                       float* __restrict__ x) {
    int i = blockIdx.x * 256 + threadIdx.x;       // < BT*DD
    int r = i >> 8, d = i & 255;
    int b = r / TT, t = r % TT;
    float v;
    if (t == 0) {
        v = clsv[d];
    } else {
        int jj = t - 1;
        if (jj < cntb[b]) {
            int g = idxb[b * KK + jj];
            v = gene_emb[(size_t)g * DD + d] + VAL[((size_t)b * KK + jj) * DD + d];
        } else {
            v = 0.0f;
        }
    }
    x[i] = v;
}

// ---------------- LayerNorm: wave per row, no barriers ----------------
__global__ __launch_bounds__(256) void ln_kernel(const float* __restrict__ X,
                                                 const float* __restrict__ s,
                                                 const float* __restrict__ bsh,
                                                 ub16* __restrict__ Y16,
                                                 float* __restrict__ Yf) {
    int w = threadIdx.x >> 6, lane = threadIdx.x & 63;
    size_t r = (size_t)blockIdx.x * 4 + w;        // BT = 4*2049 exactly
    float4 xv = *(const float4*)(X + r * 256 + lane * 4);
    float sum = xv.x + xv.y + xv.z + xv.w;
    #pragma unroll
    for (int o = 1; o < 64; o <<= 1) sum += __shfl_xor(sum, o);
    float mu = sum * (1.0f / 256.0f);
    float d0 = xv.x - mu, d1 = xv.y - mu, d2 = xv.z - mu, d3 = xv.w - mu;
    float vs = d0 * d0 + d1 * d1 + d2 * d2 + d3 * d3;
    #pragma unroll
    for (int o = 1; o < 64; o <<= 1) vs += __shfl_xor(vs, o);
    float rstd = rsqrtf(vs * (1.0f / 256.0f) + 1e-5f);
    float4 sc = *(const float4*)(s + lane * 4);
    float4 bc = *(const float4*)(bsh + lane * 4);
    float y0 = d0 * rstd * sc.x + bc.x;
    float y1 = d1 * rstd * sc.y + bc.y;
    float y2 = d2 * rstd * sc.z + bc.z;
    float y3 = d3 * rstd * sc.w + bc.w;
    if (Y16) {
        uint2 o2 = make_uint2(pk2(y0, y1), pk2(y2, y3));
        *(uint2*)(Y16 + r * 256 + lane * 4) = o2;
    } else {
        *(float4*)(Yf + r * 256 + lane * 4) = make_float4(y0, y1, y2, y3);
    }
}

// ---------------- bf16 MFMA NT-GEMM: C = act(A @ W^T + bias) (+R), 64x64 -------
__global__ __launch_bounds__(256) void gemm_bt16(const ub16* __restrict__ A,
                                                 const ub16* __restrict__ W,
                                                 const float* __restrict__ bias,
                                                 const float* __restrict__ R,
                                                 float* __restrict__ Cf,
                                                 ub16* __restrict__ Ch,
                                                 int M, int N, int K, int gelu_flag,
                                                 int qcols) {
    __shared__ ub16 As[2][64][40];
    __shared__ ub16 Ws[2][64][40];
    int tid = threadIdx.x;
    int lane = tid & 63, w = tid >> 6;
    int wr = (w >> 1) * 32, wc = (w & 1) * 32;
    int bm = blockIdx.y * 64, bn = blockIdx.x * 64;
    f32x4 acc[2][2] = {};

    int lrow = tid >> 2, lc8 = (tid & 3) * 8;
    int arow = min(bm + lrow, M - 1);
    const ub16* ap = A + (size_t)arow * K + lc8;
    const ub16* wp = W + (size_t)(bn + lrow) * K + lc8;

    int fr = lane & 15, fc = 8 * (lane >> 4);
    for (int k0 = 0; k0 < K; k0 += 64) {
        bf16x8 av0 = *(const bf16x8*)(ap + k0);
        bf16x8 av1 = *(const bf16x8*)(ap + k0 + 32);
        bf16x8 wv0 = *(const bf16x8*)(wp + k0);
        bf16x8 wv1 = *(const bf16x8*)(wp + k0 + 32);
        *(bf16x8*)&As[0][lrow][lc8] = av0;
        *(bf16x8*)&As[1][lrow][lc8] = av1;
        *(bf16x8*)&Ws[0][lrow][lc8] = wv0;
        *(bf16x8*)&Ws[1][lrow][lc8] = wv1;
        __syncthreads();
        #pragma unroll
        for (int ks = 0; ks < 2; ++ks) {
            bf16x8 a0 = *(const bf16x8*)&As[ks][wr + fr][fc];
            bf16x8 a1 = *(const bf16x8*)&As[ks][wr + 16 + fr][fc];
            bf16x8 b0 = *(const bf16x8*)&Ws[ks][wc + fr][fc];
            bf16x8 b1 = *(const bf16x8*)&Ws[ks][wc + 16 + fr][fc];
            acc[0][0] = __builtin_amdgcn_mfma_f32_16x16x32_bf16(a0, b0, acc[0][0], 0, 0, 0);
            acc[0][1] = __builtin_amdgcn_mfma_f32_16x16x32_bf16(a0, b1, acc[0][1], 0, 0, 0);
            acc[1][0] = __builtin_amdgcn_mfma_f32_16x16x32_bf16(a1, b0, acc[1][0], 0, 0, 0);
            acc[1][1] = __builtin_amdgcn_mfma_f32_16x16x32_bf16(a1, b1, acc[1][1], 0, 0, 0);
        }
        __syncthreads();
    }

    #pragma unroll
    for (int i = 0; i < 2; ++i) {
        #pragma unroll
        for (int j = 0; j < 2; ++j) {
            #pragma unroll
            for (int reg = 0; reg < 4; ++reg) {
                int gm = bm + wr + i * 16 + (lane >> 4) * 4 + reg;
                int gn = bn + wc + j * 16 + (lane & 15);
                if (gm >= M) continue;
                float v = acc[i][j][reg] + bias[gn];
                if (R) v += R[(size_t)gm * N + gn];
                if (gelu_flag) v = gelu_f(v);
                if (gn < qcols) v *= QSC;
                if (Cf) Cf[(size_t)gm * N + gn] = v;
                else    Ch[(size_t)gm * N + gn] = f2b(v);
            }
        }
    }
}

// ---------------- bf16 MFMA NT-GEMM, 64x128 tile (for N>=128 multiples) --------
__global__ __launch_bounds__(256) void gemm_bn128(const ub16* __restrict__ A,
                                                  const ub16* __restrict__ W,
                                                  const float* __restrict__ bias,
                                                  ub16* __restrict__ Ch,
                                                  int M, int N, int K, int gelu_flag,
                                                  int qcols) {
    __shared__ ub16 As[2][64][40];
    __shared__ ub16 Ws[2][128][40];
    int tid = threadIdx.x, lane = tid & 63, w = tid >> 6;
    int wr = (w >> 1) * 32, wc = (w & 1) * 64;
    int bm = blockIdx.y * 64, bn = blockIdx.x * 128;
    f32x4 acc[2][4] = {};

    int arow = tid >> 2, aseg = tid & 3, aks = aseg >> 1, aoff = (aseg & 1) * 16;
    const ub16* apg = A + (size_t)min(bm + arow, M - 1) * K + aseg * 16;
    int wrow = tid >> 1, wks = tid & 1;
    const ub16* wpg = W + (size_t)(bn + wrow) * K + wks * 32;
    int fr = lane & 15, fc = 8 * (lane >> 4);

    bf16x8 ra0 = *(const bf16x8*)apg;
    bf16x8 ra1 = *(const bf16x8*)(apg + 8);
    bf16x8 rb0 = *(const bf16x8*)wpg;
    bf16x8 rb1 = *(const bf16x8*)(wpg + 8);
    bf16x8 rb2 = *(const bf16x8*)(wpg + 16);
    bf16x8 rb3 = *(const bf16x8*)(wpg + 24);

    for (int k0 = 0; k0 < K; k0 += 64) {
        *(bf16x8*)&As[aks][arow][aoff] = ra0;
        *(bf16x8*)&As[aks][arow][aoff + 8] = ra1;
        *(bf16x8*)&Ws[wks][wrow][0]  = rb0;
        *(bf16x8*)&Ws[wks][wrow][8]  = rb1;
        *(bf16x8*)&Ws[wks][wrow][16] = rb2;
        *(bf16x8*)&Ws[wks][wrow][24] = rb3;
        __syncthreads();
        if (k0 + 64 < K) {
            ra0 = *(const bf16x8*)(apg + k0 + 64);
            ra1 = *(const bf16x8*)(apg + k0 + 72);
            rb0 = *(const bf16x8*)(wpg + k0 + 64);
            rb1 = *(const bf16x8*)(wpg + k0 + 72);
            rb2 = *(const bf16x8*)(wpg + k0 + 80);
            rb3 = *(const bf16x8*)(wpg + k0 + 88);
        }
        #pragma unroll
        for (int ks = 0; ks < 2; ++ks) {
            bf16x8 af[2], bfv[4];
            #pragma unroll
            for (int mr = 0; mr < 2; ++mr)
                af[mr] = *(const bf16x8*)&As[ks][wr + mr * 16 + fr][fc];
            #pragma unroll
            for (int nr = 0; nr < 4; ++nr)
                bfv[nr] = *(const bf16x8*)&Ws[ks][wc + nr * 16 + fr][fc];
            #pragma unroll
            for (int mr = 0; mr < 2; ++mr)
                #pragma unroll
                for (int nr = 0; nr < 4; ++nr)
                    acc[mr][nr] = __builtin_amdgcn_mfma_f32_16x16x32_bf16(
                        af[mr], bfv[nr], acc[mr][nr], 0, 0, 0);
        }
        __syncthreads();
    }

    #pragma unroll
    for (int mr = 0; mr < 2; ++mr) {
        #pragma unroll
        for (int nr = 0; nr < 4; ++nr) {
            #pragma unroll
            for (int reg = 0; reg < 4; ++reg) {
                int gm = bm + wr + mr * 16 + (lane >> 4) * 4 + reg;
                int gn = bn + wc + nr * 16 + (lane & 15);
                if (gm >= M) continue;
                float v = acc[mr][nr][reg] + bias[gn];
                if (gelu_flag) v = gelu_f(v);
                if (gn < qcols) v *= QSC;
                Ch[(size_t)gm * N + gn] = f2b(v);
            }
        }
    }
}

// ---------------- K/V cache prep: dense tiled Kc + k-permuted transposed Vt ----
__global__ __launch_bounds__(256) void kvprep(const ub16* __restrict__ qkv,
                                              ub16* __restrict__ Kc,
                                              ub16* __restrict__ Vt) {
    __shared__ unsigned vl[32][33];
    int bh = blockIdx.x, b = bh >> 3, h = bh & 7;
    int c = blockIdx.y;                 // 64-key chunk
    int tid = threadIdx.x;
    int krel = tid >> 2;                // 0..63
    int key = c * 64 + krel;
    int d8 = (tid & 3) * 8;
    U4B kv = {}, vv = {};
    if (key < TT) {
        const ub16* p = qkv + ((size_t)(b * TT + key)) * 768 + 256 + h * 32 + d8;
        kv.v = *(const bf16x8*)p;
        vv.v = *(const bf16x8*)(p + 256);
    }
    int kt = c * 2 + (krel >> 5);
    if (kt < NT)
        *(bf16x8*)(Kc + (((size_t)bh * NT + kt) * 32 + (krel & 31)) * 32 + d8) = kv.v;

    unsigned pu[4];
    #pragma unroll
    for (int j = 0; j < 4; ++j) pu[j] = __shfl_xor(vv.u[j], 4);
    if (!(krel & 1)) {
        int kp = krel >> 1;
        #pragma unroll
        for (int j = 0; j < 8; ++j) {
            unsigned mine = (vv.u[j >> 1] >> ((j & 1) * 16)) & 0xffffu;
            unsigned oth  = (pu[j >> 1] >> ((j & 1) * 16)) & 0xffffu;
            vl[d8 + j][kp] = mine | (oth << 16);
        }
    }
    __syncthreads();
    int d = tid >> 3, c8 = tid & 7;
    int kt2 = c * 2 + (c8 >> 2);
    if (kt2 < NT) {
        unsigned* vdst = (unsigned*)(Vt + (((size_t)bh * NT + kt2) * 32 + d) * 32);
        #pragma unroll
        for (int ih = 0; ih < 2; ++ih) {
            int pkr = (c8 & 3) * 4 + ih * 2;     // key-pair index 0..15 (even)
            int dp = (pkr & 1) | ((pkr & 2) << 1) | ((pkr & 4) >> 1) | (pkr & 8);
            uint2 o2 = make_uint2(vl[d][c8 * 4 + ih * 2], vl[d][c8 * 4 + ih * 2 + 1]);
            *(uint2*)(vdst + dp) = o2;
        }
    }
}

// ---------------- MFMA flash attention: 8-way split-K, fixed-m softmax --------
// grid (B*H, 65); block 512 = 8 waves sharing one 32-query tile, each wave
// every-8th key tile; partials merged in LDS. P = exp2(st) directly; pack via
// direct bf16 element casts (compiler emits v_cvt_pk_bf16_f32); tree tsum.
__global__ __launch_bounds__(512) void attn_mfma6(const ub16* __restrict__ qkv,
                                                  const ub16* __restrict__ Kc,
                                                  const ub16* __restrict__ Vt,
                                                  const int* __restrict__ cnt,
                                                  ub16* __restrict__ attno) {
    __shared__ float Olds[8][32][33];
    __shared__ float Oll[8][32];
    int bh = blockIdx.x, b = bh >> 3, h = bh & 7;
    int tid = threadIdx.x;
    int w = tid >> 6, lane = tid & 63, hi = lane >> 5, q = lane & 31;
    int qt = blockIdx.y;
    int t = qt * 32 + q;
    int nvalid = cnt[b] + 1;
    int nkt = (nvalid + 31) >> 5;
    int nfull = (nvalid & 31) ? nkt - 1 : nkt;

    int tc = min(t, TT - 1);
    const ub16* qp = qkv + ((size_t)(b * TT + tc)) * 768 + h * 32 + 8 * hi;
    bf16x8 bq0 = *(const bf16x8*)qp;        // Q pre-scaled by QSC in gemm epilogue
    bf16x8 bq1 = *(const bf16x8*)(qp + 16);

    float l = 0.0f;
    f32x16 ot = {};

    const ub16* kbase = Kc + (size_t)bh * NT * 1024 + q * 32 + 8 * hi;
    const ub16* vbase = Vt + (size_t)bh * NT * 1024 + q * 32 + 8 * hi;

    size_t cur = (size_t)min(w, NT - 1) * 1024;
    bf16x8 ka0 = *(const bf16x8*)(kbase + cur);
    bf16x8 ka1 = *(const bf16x8*)(kbase + cur + 16);
    bf16x8 va0 = *(const bf16x8*)(vbase + cur);
    bf16x8 va1 = *(const bf16x8*)(vbase + cur + 16);

    for (int kt = w; kt < nkt; kt += 8) {
        size_t nxt = (size_t)min(kt + 8, NT - 1) * 1024;
        bf16x8 nk0 = *(const bf16x8*)(kbase + nxt);
        bf16x8 nk1 = *(const bf16x8*)(kbase + nxt + 16);
        bf16x8 nv0 = *(const bf16x8*)(vbase + nxt);
        bf16x8 nv1 = *(const bf16x8*)(vbase + nxt + 16);

        f32x16 z = {};
        f32x16 st = __builtin_amdgcn_mfma_f32_32x32x16_bf16(ka0, bq0, z, 0, 0, 0);
        st = __builtin_amdgcn_mfma_f32_32x32x16_bf16(ka1, bq1, st, 0, 0, 0);

        if (kt >= nfull) {                  // only the (rare) partial tile
            int lim = nvalid - (kt << 5);
            #pragma unroll
            for (int r = 0; r < 16; ++r) {
                int off = (r & 3) + 8 * (r >> 2) + 4 * hi;
                if (off >= lim) st[r] = -1e30f;
            }
        }

        float p[16];
        #pragma unroll
        for (int r = 0; r < 16; ++r) p[r] = EXP2(st[r]);
        // tree sum (depth 4)
        float s0 = (p[0] + p[1]) + (p[2] + p[3]);
        float s1 = (p[4] + p[5]) + (p[6] + p[7]);
        float s2 = (p[8] + p[9]) + (p[10] + p[11]);
        float s3 = (p[12] + p[13]) + (p[14] + p[15]);
        l += (s0 + s1) + (s2 + s3);

        // P -> B-fragments via direct element casts (k-order matches permuted Vt)
        bf16x8 pv0, pv1;
        #pragma unroll
        for (int jj = 0; jj < 8; ++jj) {
            pv0[jj] = (__bf16)p[jj];
            pv1[jj] = (__bf16)p[8 + jj];
        }
        ot = __builtin_amdgcn_mfma_f32_32x32x16_bf16(va0, pv0, ot, 0, 0, 0);
        ot = __builtin_amdgcn_mfma_f32_32x32x16_bf16(va1, pv1, ot, 0, 0, 0);

        ka0 = nk0; ka1 = nk1; va0 = nv0; va1 = nv1;
    }

    l += __shfl_xor(l, 32);
    #pragma unroll
    for (int r = 0; r < 16; ++r) {
        int d = (r & 3) + 8 * (r >> 2) + 4 * hi;
        Olds[w][q][d] = ot[r];
    }
    if (hi == 0) Oll[w][q] = l;
    __syncthreads();

    // merge: thread -> (q row, 2-wide d group); plain sums (shared fixed m)
    int qq = tid >> 4, dg = tid & 15;
    int trow = qt * 32 + qq;
    if (trow < TT) {
        float L = 0.0f, o0 = 0.0f, o1 = 0.0f;
        #pragma unroll
        for (int ww = 0; ww < 8; ++ww) {
            L += Oll[ww][qq];
            o0 += Olds[ww][qq][dg * 2];
            o1 += Olds[ww][qq][dg * 2 + 1];
        }
        float rL = 1.0f / L;
        *(unsigned*)(attno + ((size_t)(b * TT + trow)) * 256 + h * 32 + dg * 2) =
            pk2(o0 * rL, o1 * rL);
    }
}

// ---------------- head ----------------
__global__ __launch_bounds__(512) void head_kernel(const float* __restrict__ Y,
                                                   const float* __restrict__ w1,
                                                   const float* __restrict__ b1,
                                                   const float* __restrict__ w2,
                                                   const float* __restrict__ b2,
                                                   float* __restrict__ out) {
    __shared__ float clsr[256];
    __shared__ float t1[512];
    int b = blockIdx.x, tid = threadIdx.x;
    if (tid < 256) clsr[tid] = Y[((size_t)b * TT) * DD + tid];
    __syncthreads();
    float acc = b1[tid];
    const float* w = w1 + (size_t)tid * 256;
    for (int k = 0; k < 256; ++k) acc += clsr[k] * w[k];
    t1[tid] = gelu_f(acc);
    __syncthreads();
    float acc2 = b2[tid];
    const float* wr = w2 + (size_t)tid * 512;
    for (int k = 0; k < 512; ++k) acc2 += t1[k] * wr[k];
    out[(size_t)b * 512 + tid] = acc2;
}

// ---------------- launch ----------------
extern "C" void kernel_launch(void* const* d_in, const int* in_sizes, int n_in,
                              void* d_out, int out_size, void* d_ws, size_t ws_size,
                              hipStream_t stream) {
    (void)in_sizes; (void)n_in; (void)out_size; (void)ws_size;
    const float* expr     = (const float*)d_in[0];
    const float* gene_emb = (const float*)d_in[1];
    const float* ep_w1    = (const float*)d_in[2];
    const float* ep_b1    = (const float*)d_in[3];
    const float* ep_w2    = (const float*)d_in[4];
    const float* ep_b2    = (const float*)d_in[5];
    const float* clsv     = (const float*)d_in[6];
    const float* ln1_s    = (const float*)d_in[7];
    const float* ln1_b    = (const float*)d_in[8];
    const float* qkv_w    = (const float*)d_in[9];
    const float* qkv_b    = (const float*)d_in[10];
    const float* out_w    = (const float*)d_in[11];
    const float* out_b    = (const float*)d_in[12];
    const float* ln2_s    = (const float*)d_in[13];
    const float* ln2_b    = (const float*)d_in[14];
    const float* ff_w1    = (const float*)d_in[15];
    const float* ff_b1    = (const float*)d_in[16];
    const float* ff_w2    = (const float*)d_in[17];
    const float* ff_b2    = (const float*)d_in[18];
    const float* fn_s     = (const float*)d_in[19];
    const float* fn_b     = (const float*)d_in[20];
    const float* pr_w1    = (const float*)d_in[21];
    const float* pr_b1    = (const float*)d_in[22];
    const float* pr_w2    = (const float*)d_in[23];
    const float* pr_b2    = (const float*)d_in[24];
    float* outp = (float*)d_out;

    const size_t KVSZ = (size_t)32 * NT * 1024;

    // workspace layout
    float* x   = (float*)d_ws;                       // BT*256 f32
    float* VAL = x + (size_t)BT * 256;               // 8192*256 f32; reused as Vt + final-LN out
    ub16* y16   = (ub16*)(VAL + (size_t)8192 * 256);
    ub16* qkv16 = y16 + (size_t)BT * 256;
    ub16* att16 = qkv16 + (size_t)BT * 768;
    ub16* ff116 = att16 + (size_t)BT * 256;
    ub16* kc_h  = ff116 + (size_t)BT * 1024;
    ub16* wqkv  = kc_h + KVSZ;
    ub16* wout  = wqkv + (size_t)LL * 768 * 256;
    ub16* wff1  = wout + (size_t)LL * 256 * 256;
    ub16* wff2  = wff1 + (size_t)LL * 1024 * 256;
    ub16* wep2  = wff2 + (size_t)LL * 256 * 1024;
    int*  idxb  = (int*)(wep2 + (size_t)256 * 256);
    int*  cntb  = idxb + BB * KK;
    unsigned* prefwant = (unsigned*)(cntb + BB);
    unsigned* histg    = prefwant + BB * 2;
    int* blkcnt  = (int*)(histg + BB * 256);
    int* blkbase = blkcnt + BB * TCH * 2;
    ub16* H16 = kc_h;
    ub16* Kc  = kc_h;
    ub16* Vt  = (ub16*)VAL;

    // 1) top-K (multi-block radix select)
    topk_init<<<1, 1024, 0, stream>>>(prefwant, histg);
    for (int p = 3; p >= 0; --p) {
        topk_hist<<<dim3(BB, TCH), 1024, 0, stream>>>(expr, prefwant, histg, p);
        topk_select<<<BB, 64, 0, stream>>>(prefwant, histg, p);
    }
    topk_c1<<<dim3(BB, TCH), 1024, 0, stream>>>(expr, prefwant, blkcnt);
    topk_c2<<<BB, 64, 0, stream>>>(prefwant, blkcnt, blkbase, cntb);
    topk_c3<<<dim3(BB, TCH), 1024, 0, stream>>>(expr, prefwant, blkbase, idxb);

    // 2) weights -> bf16
    cvt_bf16_kernel<<<(LL*768*256 + 255)/256, 256, 0, stream>>>(qkv_w, wqkv, LL*768*256);
    cvt_bf16_kernel<<<(LL*256*256 + 255)/256, 256, 0, stream>>>(out_w, wout, LL*256*256);
    cvt_bf16_kernel<<<(LL*1024*256 + 255)/256, 256, 0, stream>>>(ff_w1, wff1, LL*1024*256);
    cvt_bf16_kernel<<<(LL*256*1024 + 255)/256, 256, 0, stream>>>(ff_w2, wff2, LL*256*1024);
    cvt_bf16_kernel<<<(256*256 + 255)/256, 256, 0, stream>>>(ep_w2, wep2, 256*256);

    // 3) token embeddings
    build_h_kernel<<<(BB * KK * DD) / 256, 256, 0, stream>>>(expr, idxb, cntb, ep_w1, ep_b1, H16);
    gemm_bt16<<<dim3(4, 128), 256, 0, stream>>>(H16, wep2, ep_b2, nullptr, VAL, nullptr,
                                                8192, 256, 256, 0, 0);
    assemble_kernel<<<BT, 256, 0, stream>>>(VAL, gene_emb, clsv, idxb, cntb, x);

    // 4) transformer layers
    for (int i = 0; i < LL; ++i) {
        ln_kernel<<<BT / 4, 256, 0, stream>>>(x, ln1_s + i * DD, ln1_b + i * DD, y16, nullptr);
        gemm_bn128<<<dim3(6, 129), 256, 0, stream>>>(y16, wqkv + (size_t)i * 768 * 256,
                                                     qkv_b + i * 768, qkv16,
                                                     BT, 768, 256, 0, 256);
        kvprep<<<dim3(BB * HH, 33), 256, 0, stream>>>(qkv16, Kc, Vt);
        attn_mfma6<<<dim3(BB * HH, NT), 512, 0, stream>>>(qkv16, Kc, Vt, cntb, att16);
        gemm_bt16<<<dim3(4, 129), 256, 0, stream>>>(att16, wout + (size_t)i * 256 * 256,
                                                    out_b + i * 256, x, x, nullptr,
                                                    BT, 256, 256, 0, 0);
        ln_kernel<<<BT / 4, 256, 0, stream>>>(x, ln2_s + i * DD, ln2_b + i * DD, y16, nullptr);
        gemm_bn128<<<dim3(8, 129), 256, 0, stream>>>(y16, wff1 + (size_t)i * 1024 * 256,
                                                     ff_b1 + i * 1024, ff116,
                                                     BT, 1024, 256, 1, 0);
        gemm_bt16<<<dim3(4, 129), 256, 0, stream>>>(ff116, wff2 + (size_t)i * 256 * 1024,
                                                    ff_b2 + i * 256, x, x, nullptr,
                                                    BT, 256, 1024, 0, 0);
    }

    // 5) final LN + head
    ln_kernel<<<BT / 4, 256, 0, stream>>>(x, fn_s, fn_b, nullptr, VAL);
    head_kernel<<<BB, 512, 0, stream>>>(VAL, pr_w1, pr_b1, pr_w2, pr_b2, outp);
}

// Round 10
// 825.190 us; speedup vs baseline: 1.2529x; 1.0560x over previous
//
#include <hip/hip_runtime.h>
#include <hip/hip_bf16.h>
#include <math.h>

// Problem constants
#define GG 33538
#define DD 256
#define LL 6
#define HH 8
#define KK 2048
#define BB 4
#define TT 2049          // K+1 tokens
#define BT (BB*TT)       // 8196
#define NT 65            // 32-key tiles per (b,h)
#define TCH 7            // topk blocks per batch row (7*5120 >= GG)
#define QSC (0.17677669529663688f * 1.44269504088896340f)   // 1/sqrt(32) * log2e

#if __has_builtin(__builtin_amdgcn_exp2f)
#define EXP2(x) __builtin_amdgcn_exp2f(x)
#else
#define EXP2(x) exp2f(x)
#endif

typedef __bf16 bf16x8 __attribute__((ext_vector_type(8)));
typedef float f32x4 __attribute__((ext_vector_type(4)));
typedef float f32x16 __attribute__((ext_vector_type(16)));
typedef unsigned short ub16;

union BW { __bf16 h; ub16 u; };
__device__ __forceinline__ ub16 f2b(float x) { BW w; w.h = (__bf16)x; return w.u; }
__device__ __forceinline__ unsigned pk2(float a, float b) {
    return (unsigned)f2b(a) | ((unsigned)f2b(b) << 16);
}
union U4B { unsigned u[4]; bf16x8 v; };

__device__ __forceinline__ float gelu_f(float x) {
    return 0.5f * x * (1.0f + erff(x * 0.70710678118654752440f));
}

__device__ __forceinline__ unsigned to_key(float x) {
    unsigned u = __float_as_uint(x);
    return (u & 0x80000000u) ? ~u : (u | 0x80000000u);
}

// ---------------- Top-K phase kernels (multi-block radix select) ----------------
__device__ int block_scan_excl_1024(int v, int* shw) {
    int lane = threadIdx.x & 63, w = threadIdx.x >> 6;
    int x = v;
    #pragma unroll
    for (int o = 1; o < 64; o <<= 1) {
        int t = __shfl_up(x, o, 64);
        if (lane >= o) x += t;
    }
    if (lane == 63) shw[w] = x;
    __syncthreads();
    if (w == 0) {
        int y = (lane < 16) ? shw[lane] : 0;
        #pragma unroll
        for (int o = 1; o < 16; o <<= 1) {
            int t = __shfl_up(y, o, 64);
            if (lane >= o) y += t;
        }
        if (lane < 16) shw[lane] = y;
    }
    __syncthreads();
    int off = (w == 0) ? 0 : shw[w - 1];
    return off + x - v;   // exclusive prefix
}

__global__ void topk_init(unsigned* __restrict__ prefwant, unsigned* __restrict__ histg) {
    int i = threadIdx.x;
    if (i < BB * 256) histg[i] = 0u;
    if (i < BB) { prefwant[2 * i] = 0u; prefwant[2 * i + 1] = KK; }
}

__global__ __launch_bounds__(1024) void topk_hist(const float* __restrict__ expr,
                                                  const unsigned* __restrict__ prefwant,
                                                  unsigned* __restrict__ histg, int pass) {
    __shared__ unsigned lh[16][256];
    int b = blockIdx.x, blk = blockIdx.y, tid = threadIdx.x, wv = tid >> 6;
    for (int i = tid; i < 16 * 256; i += 1024) ((unsigned*)lh)[i] = 0u;
    __syncthreads();
    unsigned prefix = prefwant[2 * b];
    int shift = pass * 8;
    unsigned pmask = (pass == 3) ? 0u : (0xFFFFFFFFu << (shift + 8));
    const float* row = expr + (size_t)b * GG;
    int base = blk * 5120;
    #pragma unroll
    for (int j = 0; j < 5; ++j) {
        int g = base + j * 1024 + tid;
        if (g < GG) {
            unsigned key = to_key(row[g]);
            if ((key & pmask) == (prefix & pmask))
                atomicAdd(&lh[wv][(key >> shift) & 255u], 1u);
        }
    }
    __syncthreads();
    if (tid < 256) {
        unsigned s = 0;
        #pragma unroll
        for (int j = 0; j < 16; ++j) s += lh[j][tid];
        if (s) atomicAdd(&histg[b * 256 + tid], s);
    }
}

__global__ void topk_select(unsigned* __restrict__ prefwant,
                            unsigned* __restrict__ histg, int pass) {
    int b = blockIdx.x, lane = threadIdx.x;      // 64 threads
    int shift = pass * 8;
    unsigned pref = prefwant[2 * b];
    int want = (int)prefwant[2 * b + 1];
    unsigned cc[4];
    #pragma unroll
    for (int j = 0; j < 4; ++j) cc[j] = histg[b * 256 + lane * 4 + j];
    int s = (int)(cc[0] + cc[1] + cc[2] + cc[3]);
    int incl = s;
    #pragma unroll
    for (int o = 1; o < 64; o <<= 1) { int t = __shfl_up(incl, o); if (lane >= o) incl += t; }
    int total = __shfl(incl, 63);
    int a3 = total - incl;                        // count in bins above lane's top bin
    int a2 = a3 + (int)cc[3], a1 = a2 + (int)cc[2], a0 = a1 + (int)cc[1];
    int av[4] = {a0, a1, a2, a3};
    #pragma unroll
    for (int j = 0; j < 4; ++j) {
        if (av[j] < want && av[j] + (int)cc[j] >= want) {
            prefwant[2 * b] = pref | ((unsigned)(lane * 4 + j) << shift);
            prefwant[2 * b + 1] = (unsigned)(want - av[j]);
        }
    }
    #pragma unroll
    for (int j = 0; j < 4; ++j) histg[b * 256 + lane * 4 + j] = 0u;
}

__global__ __launch_bounds__(1024) void topk_c1(const float* __restrict__ expr,
                                                const unsigned* __restrict__ prefwant,
                                                int* __restrict__ blkcnt) {
    __shared__ int sred[16][2];
    int b = blockIdx.x, blk = blockIdx.y, tid = threadIdx.x;
    unsigned kth = prefwant[2 * b];
    const float* row = expr + (size_t)b * GG;
    int start = blk * 5120 + tid * 5;
    int eq = 0, gtp = 0;
    #pragma unroll
    for (int j = 0; j < 5; ++j) {
        int g = start + j;
        if (g < GG) {
            float e = row[g];
            unsigned key = to_key(e);
            eq += (key == kth);
            gtp += (key > kth && e > 0.0f);
        }
    }
    #pragma unroll
    for (int o = 1; o < 64; o <<= 1) { eq += __shfl_xor(eq, o); gtp += __shfl_xor(gtp, o); }
    if ((tid & 63) == 0) { sred[tid >> 6][0] = eq; sred[tid >> 6][1] = gtp; }
    __syncthreads();
    if (tid == 0) {
        int te = 0, tg = 0;
        #pragma unroll
        for (int i = 0; i < 16; ++i) { te += sred[i][0]; tg += sred[i][1]; }
        blkcnt[(b * TCH + blk) * 2] = te;
        blkcnt[(b * TCH + blk) * 2 + 1] = tg;
    }
}

__global__ void topk_c2(const unsigned* __restrict__ prefwant,
                        const int* __restrict__ blkcnt,
                        int* __restrict__ blkbase, int* __restrict__ cntout) {
    int b = blockIdx.x, lane = threadIdx.x;      // 64 threads
    int eq = 0, gtp = 0;
    if (lane < TCH) {
        eq = blkcnt[(b * TCH + lane) * 2];
        gtp = blkcnt[(b * TCH + lane) * 2 + 1];
    }
    int want = (int)prefwant[2 * b + 1];
    bool kthpos = prefwant[2 * b] > 0x80000000u;
    int incl = eq;
    #pragma unroll
    for (int o = 1; o < 8; o <<= 1) { int t = __shfl_up(incl, o); if (lane >= o) incl += t; }
    int eqb = incl - eq;
    int eqsel = kthpos ? min(max(want - eqb, 0), eq) : 0;
    int act = gtp + eqsel;
    int incl2 = act;
    #pragma unroll
    for (int o = 1; o < 8; o <<= 1) { int t = __shfl_up(incl2, o); if (lane >= o) incl2 += t; }
    int outb = incl2 - act;
    if (lane < TCH) {
        blkbase[(b * TCH + lane) * 2] = eqb;
        blkbase[(b * TCH + lane) * 2 + 1] = outb;
    }
    if (lane == TCH - 1) cntout[b] = incl2;
}

__global__ __launch_bounds__(1024) void topk_c3(const float* __restrict__ expr,
                                                const unsigned* __restrict__ prefwant,
                                                const int* __restrict__ blkbase,
                                                int* __restrict__ idxout) {
    __shared__ int shw[16];
    int b = blockIdx.x, blk = blockIdx.y, tid = threadIdx.x;
    unsigned kth = prefwant[2 * b];
    int want = (int)prefwant[2 * b + 1];
    const float* row = expr + (size_t)b * GG;
    int start = blk * 5120 + tid * 5;
    int eqt = 0;
    #pragma unroll
    for (int j = 0; j < 5; ++j) {
        int g = start + j;
        if (g < GG) eqt += (to_key(row[g]) == kth);
    }
    int eqbase = blkbase[(b * TCH + blk) * 2] + block_scan_excl_1024(eqt, shw);
    __syncthreads();
    int actt = 0;
    {
        int leq = 0;
        #pragma unroll
        for (int j = 0; j < 5; ++j) {
            int g = start + j;
            if (g < GG) {
                float e = row[g];
                unsigned key = to_key(e);
                bool sel = (key > kth) || (key == kth && (eqbase + leq) < want);
                leq += (key == kth);
                actt += (sel && e > 0.0f) ? 1 : 0;
            }
        }
    }
    int pos = blkbase[(b * TCH + blk) * 2 + 1] + block_scan_excl_1024(actt, shw);
    {
        int leq = 0;
        #pragma unroll
        for (int j = 0; j < 5; ++j) {
            int g = start + j;
            if (g < GG) {
                float e = row[g];
                unsigned key = to_key(e);
                bool sel = (key > kth) || (key == kth && (eqbase + leq) < want);
                leq += (key == kth);
                if (sel && e > 0.0f) idxout[b * KK + pos++] = g;
            }
        }
    }
}

// ---------------- weight fp32 -> bf16 ----------------
__global__ __launch_bounds__(256) void cvt_bf16_kernel(const float* __restrict__ s,
                                                       ub16* __restrict__ d, int n) {
    int i = blockIdx.x * 256 + threadIdx.x;
    if (i < n) d[i] = f2b(s[i]);
}

// ---------------- Token embedding ----------------
__global__ __launch_bounds__(256) void build_h_kernel(const float* __restrict__ expr,
                                                      const int* __restrict__ idxb,
                                                      const int* __restrict__ cntb,
                                                      const float* __restrict__ ep_w1,
                                                      const float* __restrict__ ep_b1,
                                                      ub16* __restrict__ H) {
    int i = blockIdx.x * 256 + threadIdx.x;       // < BB*KK*DD
    int r = i >> 8, d = i & 255;
    int b = r >> 11, jj = r & (KK - 1);
    float v = 0.0f;
    if (jj < cntb[b]) {
        int g = idxb[b * KK + jj];
        float e = expr[(size_t)b * GG + g];
        v = gelu_f(e * ep_w1[d] + ep_b1[d]);
    }
    H[i] = f2b(v);
}

__global__ __launch_bounds__(256) void assemble_kernel(const float* __restrict__ VAL,
                                                       const float* __restrict__ gene_emb,
                                                       const float* __restrict__ clsv,
                                                       const int* __restrict__ idxb,
                                                       const int* __restrict__ cntb,
                                                       float* __restrict__ x) {
    int i = blockIdx.x * 256 + threadIdx.x;       // < BT*DD
    int r = i >> 8, d = i & 255;
    int b = r / TT, t = r % TT;
    float v;
    if (t == 0) {
        v = clsv[d];
    } else {
        int jj = t - 1;
        if (jj < cntb[b]) {
            int g = idxb[b * KK + jj];
            v = gene_emb[(size_t)g * DD + d] + VAL[((size_t)b * KK + jj) * DD + d];
        } else {
            v = 0.0f;
        }
    }
    x[i] = v;
}

// ---------------- LayerNorm: wave per row, no barriers ----------------
__global__ __launch_bounds__(256) void ln_kernel(const float* __restrict__ X,
                                                 const float* __restrict__ s,
                                                 const float* __restrict__ bsh,
                                                 ub16* __restrict__ Y16,
                                                 float* __restrict__ Yf) {
    int w = threadIdx.x >> 6, lane = threadIdx.x & 63;
    size_t r = (size_t)blockIdx.x * 4 + w;        // BT = 4*2049 exactly
    float4 xv = *(const float4*)(X + r * 256 + lane * 4);
    float sum = xv.x + xv.y + xv.z + xv.w;
    #pragma unroll
    for (int o = 1; o < 64; o <<= 1) sum += __shfl_xor(sum, o);
    float mu = sum * (1.0f / 256.0f);
    float d0 = xv.x - mu, d1 = xv.y - mu, d2 = xv.z - mu, d3 = xv.w - mu;
    float vs = d0 * d0 + d1 * d1 + d2 * d2 + d3 * d3;
    #pragma unroll
    for (int o = 1; o < 64; o <<= 1) vs += __shfl_xor(vs, o);
    float rstd = rsqrtf(vs * (1.0f / 256.0f) + 1e-5f);
    float4 sc = *(const float4*)(s + lane * 4);
    float4 bc = *(const float4*)(bsh + lane * 4);
    float y0 = d0 * rstd * sc.x + bc.x;
    float y1 = d1 * rstd * sc.y + bc.y;
    float y2 = d2 * rstd * sc.z + bc.z;
    float y3 = d3 * rstd * sc.w + bc.w;
    if (Y16) {
        uint2 o2 = make_uint2(pk2(y0, y1), pk2(y2, y3));
        *(uint2*)(Y16 + r * 256 + lane * 4) = o2;
    } else {
        *(float4*)(Yf + r * 256 + lane * 4) = make_float4(y0, y1, y2, y3);
    }
}

// ---------------- bf16 MFMA NT-GEMM: C = act(A @ W^T + bias) (+R), 64x64 -------
__global__ __launch_bounds__(256) void gemm_bt16(const ub16* __restrict__ A,
                                                 const ub16* __restrict__ W,
                                                 const float* __restrict__ bias,
                                                 const float* __restrict__ R,
                                                 float* __restrict__ Cf,
                                                 ub16* __restrict__ Ch,
                                                 int M, int N, int K, int gelu_flag,
                                                 int qcols) {
    __shared__ ub16 As[2][64][40];
    __shared__ ub16 Ws[2][64][40];
    int tid = threadIdx.x;
    int lane = tid & 63, w = tid >> 6;
    int wr = (w >> 1) * 32, wc = (w & 1) * 32;
    int bm = blockIdx.y * 64, bn = blockIdx.x * 64;
    f32x4 acc[2][2] = {};

    int lrow = tid >> 2, lc8 = (tid & 3) * 8;
    int arow = min(bm + lrow, M - 1);
    const ub16* ap = A + (size_t)arow * K + lc8;
    const ub16* wp = W + (size_t)(bn + lrow) * K + lc8;

    int fr = lane & 15, fc = 8 * (lane >> 4);
    for (int k0 = 0; k0 < K; k0 += 64) {
        bf16x8 av0 = *(const bf16x8*)(ap + k0);
        bf16x8 av1 = *(const bf16x8*)(ap + k0 + 32);
        bf16x8 wv0 = *(const bf16x8*)(wp + k0);
        bf16x8 wv1 = *(const bf16x8*)(wp + k0 + 32);
        *(bf16x8*)&As[0][lrow][lc8] = av0;
        *(bf16x8*)&As[1][lrow][lc8] = av1;
        *(bf16x8*)&Ws[0][lrow][lc8] = wv0;
        *(bf16x8*)&Ws[1][lrow][lc8] = wv1;
        __syncthreads();
        #pragma unroll
        for (int ks = 0; ks < 2; ++ks) {
            bf16x8 a0 = *(const bf16x8*)&As[ks][wr + fr][fc];
            bf16x8 a1 = *(const bf16x8*)&As[ks][wr + 16 + fr][fc];
            bf16x8 b0 = *(const bf16x8*)&Ws[ks][wc + fr][fc];
            bf16x8 b1 = *(const bf16x8*)&Ws[ks][wc + 16 + fr][fc];
            acc[0][0] = __builtin_amdgcn_mfma_f32_16x16x32_bf16(a0, b0, acc[0][0], 0, 0, 0);
            acc[0][1] = __builtin_amdgcn_mfma_f32_16x16x32_bf16(a0, b1, acc[0][1], 0, 0, 0);
            acc[1][0] = __builtin_amdgcn_mfma_f32_16x16x32_bf16(a1, b0, acc[1][0], 0, 0, 0);
            acc[1][1] = __builtin_amdgcn_mfma_f32_16x16x32_bf16(a1, b1, acc[1][1], 0, 0, 0);
        }
        __syncthreads();
    }

    #pragma unroll
    for (int i = 0; i < 2; ++i) {
        #pragma unroll
        for (int j = 0; j < 2; ++j) {
            #pragma unroll
            for (int reg = 0; reg < 4; ++reg) {
                int gm = bm + wr + i * 16 + (lane >> 4) * 4 + reg;
                int gn = bn + wc + j * 16 + (lane & 15);
                if (gm >= M) continue;
                float v = acc[i][j][reg] + bias[gn];
                if (R) v += R[(size_t)gm * N + gn];
                if (gelu_flag) v = gelu_f(v);
                if (gn < qcols) v *= QSC;
                if (Cf) Cf[(size_t)gm * N + gn] = v;
                else    Ch[(size_t)gm * N + gn] = f2b(v);
            }
        }
    }
}

// ---------------- bf16 MFMA NT-GEMM, 64x128 tile (for N>=128 multiples) --------
__global__ __launch_bounds__(256) void gemm_bn128(const ub16* __restrict__ A,
                                                  const ub16* __restrict__ W,
                                                  const float* __restrict__ bias,
                                                  ub16* __restrict__ Ch,
                                                  int M, int N, int K, int gelu_flag,
                                                  int qcols) {
    __shared__ ub16 As[2][64][40];
    __shared__ ub16 Ws[2][128][40];
    int tid = threadIdx.x, lane = tid & 63, w = tid >> 6;
    int wr = (w >> 1) * 32, wc = (w & 1) * 64;
    int bm = blockIdx.y * 64, bn = blockIdx.x * 128;
    f32x4 acc[2][4] = {};

    int arow = tid >> 2, aseg = tid & 3, aks = aseg >> 1, aoff = (aseg & 1) * 16;
    const ub16* apg = A + (size_t)min(bm + arow, M - 1) * K + aseg * 16;
    int wrow = tid >> 1, wks = tid & 1;
    const ub16* wpg = W + (size_t)(bn + wrow) * K + wks * 32;
    int fr = lane & 15, fc = 8 * (lane >> 4);

    bf16x8 ra0 = *(const bf16x8*)apg;
    bf16x8 ra1 = *(const bf16x8*)(apg + 8);
    bf16x8 rb0 = *(const bf16x8*)wpg;
    bf16x8 rb1 = *(const bf16x8*)(wpg + 8);
    bf16x8 rb2 = *(const bf16x8*)(wpg + 16);
    bf16x8 rb3 = *(const bf16x8*)(wpg + 24);

    for (int k0 = 0; k0 < K; k0 += 64) {
        *(bf16x8*)&As[aks][arow][aoff] = ra0;
        *(bf16x8*)&As[aks][arow][aoff + 8] = ra1;
        *(bf16x8*)&Ws[wks][wrow][0]  = rb0;
        *(bf16x8*)&Ws[wks][wrow][8]  = rb1;
        *(bf16x8*)&Ws[wks][wrow][16] = rb2;
        *(bf16x8*)&Ws[wks][wrow][24] = rb3;
        __syncthreads();
        if (k0 + 64 < K) {
            ra0 = *(const bf16x8*)(apg + k0 + 64);
            ra1 = *(const bf16x8*)(apg + k0 + 72);
            rb0 = *(const bf16x8*)(wpg + k0 + 64);
            rb1 = *(const bf16x8*)(wpg + k0 + 72);
            rb2 = *(const bf16x8*)(wpg + k0 + 80);
            rb3 = *(const bf16x8*)(wpg + k0 + 88);
        }
        #pragma unroll
        for (int ks = 0; ks < 2; ++ks) {
            bf16x8 af[2], bfv[4];
            #pragma unroll
            for (int mr = 0; mr < 2; ++mr)
                af[mr] = *(const bf16x8*)&As[ks][wr + mr * 16 + fr][fc];
            #pragma unroll
            for (int nr = 0; nr < 4; ++nr)
                bfv[nr] = *(const bf16x8*)&Ws[ks][wc + nr * 16 + fr][fc];
            #pragma unroll
            for (int mr = 0; mr < 2; ++mr)
                #pragma unroll
                for (int nr = 0; nr < 4; ++nr)
                    acc[mr][nr] = __builtin_amdgcn_mfma_f32_16x16x32_bf16(
                        af[mr], bfv[nr], acc[mr][nr], 0, 0, 0);
        }
        __syncthreads();
    }

    #pragma unroll
    for (int mr = 0; mr < 2; ++mr) {
        #pragma unroll
        for (int nr = 0; nr < 4; ++nr) {
            #pragma unroll
            for (int reg = 0; reg < 4; ++reg) {
                int gm = bm + wr + mr * 16 + (lane >> 4) * 4 + reg;
                int gn = bn + wc + nr * 16 + (lane & 15);
                if (gm >= M) continue;
                float v = acc[mr][nr][reg] + bias[gn];
                if (gelu_flag) v = gelu_f(v);
                if (gn < qcols) v *= QSC;
                Ch[(size_t)gm * N + gn] = f2b(v);
            }
        }
    }
}

// ---------------- K/V cache prep: dense tiled Kc + k-permuted transposed Vt ----
__global__ __launch_bounds__(256) void kvprep(const ub16* __restrict__ qkv,
                                              ub16* __restrict__ Kc,
                                              ub16* __restrict__ Vt) {
    __shared__ unsigned vl[32][33];
    int bh = blockIdx.x, b = bh >> 3, h = bh & 7;
    int c = blockIdx.y;                 // 64-key chunk
    int tid = threadIdx.x;
    int krel = tid >> 2;                // 0..63
    int key = c * 64 + krel;
    int d8 = (tid & 3) * 8;
    U4B kv = {}, vv = {};
    if (key < TT) {
        const ub16* p = qkv + ((size_t)(b * TT + key)) * 768 + 256 + h * 32 + d8;
        kv.v = *(const bf16x8*)p;
        vv.v = *(const bf16x8*)(p + 256);
    }
    int kt = c * 2 + (krel >> 5);
    if (kt < NT)
        *(bf16x8*)(Kc + (((size_t)bh * NT + kt) * 32 + (krel & 31)) * 32 + d8) = kv.v;

    unsigned pu[4];
    #pragma unroll
    for (int j = 0; j < 4; ++j) pu[j] = __shfl_xor(vv.u[j], 4);
    if (!(krel & 1)) {
        int kp = krel >> 1;
        #pragma unroll
        for (int j = 0; j < 8; ++j) {
            unsigned mine = (vv.u[j >> 1] >> ((j & 1) * 16)) & 0xffffu;
            unsigned oth  = (pu[j >> 1] >> ((j & 1) * 16)) & 0xffffu;
            vl[d8 + j][kp] = mine | (oth << 16);
        }
    }
    __syncthreads();
    int d = tid >> 3, c8 = tid & 7;
    int kt2 = c * 2 + (c8 >> 2);
    if (kt2 < NT) {
        unsigned* vdst = (unsigned*)(Vt + (((size_t)bh * NT + kt2) * 32 + d) * 32);
        #pragma unroll
        for (int ih = 0; ih < 2; ++ih) {
            int pkr = (c8 & 3) * 4 + ih * 2;     // key-pair index 0..15 (even)
            int dp = (pkr & 1) | ((pkr & 2) << 1) | ((pkr & 4) >> 1) | (pkr & 8);
            uint2 o2 = make_uint2(vl[d][c8 * 4 + ih * 2], vl[d][c8 * 4 + ih * 2 + 1]);
            *(uint2*)(vdst + dp) = o2;
        }
    }
}

// ---------------- MFMA flash attention: 4-way split-K, fixed-m softmax --------
// grid (B*H, 65); block 256 = 4 waves sharing one 32-query tile, each wave
// every-4th key tile; partials merged in LDS. P = exp2(st) directly; pack via
// direct bf16 element casts; tree tsum. (R9 trims at R6's occupancy geometry.)
__global__ __launch_bounds__(256) void attn_mfma7(const ub16* __restrict__ qkv,
                                                  const ub16* __restrict__ Kc,
                                                  const ub16* __restrict__ Vt,
                                                  const int* __restrict__ cnt,
                                                  ub16* __restrict__ attno) {
    __shared__ float Olds[4][32][33];
    __shared__ float Oll[4][32];
    int bh = blockIdx.x, b = bh >> 3, h = bh & 7;
    int tid = threadIdx.x;
    int w = tid >> 6, lane = tid & 63, hi = lane >> 5, q = lane & 31;
    int qt = blockIdx.y;
    int t = qt * 32 + q;
    int nvalid = cnt[b] + 1;
    int nkt = (nvalid + 31) >> 5;
    int nfull = (nvalid & 31) ? nkt - 1 : nkt;

    int tc = min(t, TT - 1);
    const ub16* qp = qkv + ((size_t)(b * TT + tc)) * 768 + h * 32 + 8 * hi;
    bf16x8 bq0 = *(const bf16x8*)qp;        // Q pre-scaled by QSC in gemm epilogue
    bf16x8 bq1 = *(const bf16x8*)(qp + 16);

    float l = 0.0f;
    f32x16 ot = {};

    const ub16* kbase = Kc + (size_t)bh * NT * 1024 + q * 32 + 8 * hi;
    const ub16* vbase = Vt + (size_t)bh * NT * 1024 + q * 32 + 8 * hi;

    size_t cur = (size_t)min(w, NT - 1) * 1024;
    bf16x8 ka0 = *(const bf16x8*)(kbase + cur);
    bf16x8 ka1 = *(const bf16x8*)(kbase + cur + 16);
    bf16x8 va0 = *(const bf16x8*)(vbase + cur);
    bf16x8 va1 = *(const bf16x8*)(vbase + cur + 16);

    for (int kt = w; kt < nkt; kt += 4) {
        size_t nxt = (size_t)min(kt + 4, NT - 1) * 1024;
        bf16x8 nk0 = *(const bf16x8*)(kbase + nxt);
        bf16x8 nk1 = *(const bf16x8*)(kbase + nxt + 16);
        bf16x8 nv0 = *(const bf16x8*)(vbase + nxt);
        bf16x8 nv1 = *(const bf16x8*)(vbase + nxt + 16);

        f32x16 z = {};
        f32x16 st = __builtin_amdgcn_mfma_f32_32x32x16_bf16(ka0, bq0, z, 0, 0, 0);
        st = __builtin_amdgcn_mfma_f32_32x32x16_bf16(ka1, bq1, st, 0, 0, 0);

        if (kt >= nfull) {                  // only the (rare) partial tile
            int lim = nvalid - (kt << 5);
            #pragma unroll
            for (int r = 0; r < 16; ++r) {
                int off = (r & 3) + 8 * (r >> 2) + 4 * hi;
                if (off >= lim) st[r] = -1e30f;
            }
        }

        float p[16];
        #pragma unroll
        for (int r = 0; r < 16; ++r) p[r] = EXP2(st[r]);
        // tree sum (depth 4)
        float s0 = (p[0] + p[1]) + (p[2] + p[3]);
        float s1 = (p[4] + p[5]) + (p[6] + p[7]);
        float s2 = (p[8] + p[9]) + (p[10] + p[11]);
        float s3 = (p[12] + p[13]) + (p[14] + p[15]);
        l += (s0 + s1) + (s2 + s3);

        // P -> B-fragments via direct element casts (k-order matches permuted Vt)
        bf16x8 pv0, pv1;
        #pragma unroll
        for (int jj = 0; jj < 8; ++jj) {
            pv0[jj] = (__bf16)p[jj];
            pv1[jj] = (__bf16)p[8 + jj];
        }
        ot = __builtin_amdgcn_mfma_f32_32x32x16_bf16(va0, pv0, ot, 0, 0, 0);
        ot = __builtin_amdgcn_mfma_f32_32x32x16_bf16(va1, pv1, ot, 0, 0, 0);

        ka0 = nk0; ka1 = nk1; va0 = nv0; va1 = nv1;
    }

    l += __shfl_xor(l, 32);
    #pragma unroll
    for (int r = 0; r < 16; ++r) {
        int d = (r & 3) + 8 * (r >> 2) + 4 * hi;
        Olds[w][q][d] = ot[r];
    }
    if (hi == 0) Oll[w][q] = l;
    __syncthreads();

    // merge: thread -> (q row, 4-wide d group); plain sums (shared fixed m)
    int qq = tid >> 3, dg = tid & 7;
    int trow = qt * 32 + qq;
    if (trow < TT) {
        float L = Oll[0][qq] + Oll[1][qq] + Oll[2][qq] + Oll[3][qq];
        float rL = 1.0f / L;
        float o[4];
        #pragma unroll
        for (int j = 0; j < 4; ++j) {
            int d = dg * 4 + j;
            o[j] = (Olds[0][qq][d] + Olds[1][qq][d] +
                    Olds[2][qq][d] + Olds[3][qq][d]) * rL;
        }
        uint2 o2 = make_uint2(pk2(o[0], o[1]), pk2(o[2], o[3]));
        *(uint2*)(attno + ((size_t)(b * TT + trow)) * 256 + h * 32 + dg * 4) = o2;
    }
}

// ---------------- head: wave-per-output, coalesced ----------------
// phase 1: t1[b][o] = gelu(cls[b] . w1[o] + b1[o]);  grid (BB, 128), block 256
__global__ __launch_bounds__(256) void head1_kernel(const float* __restrict__ Y,
                                                    const float* __restrict__ w1,
                                                    const float* __restrict__ b1,
                                                    float* __restrict__ t1) {
    int b = blockIdx.x, w = threadIdx.x >> 6, lane = threadIdx.x & 63;
    int o = blockIdx.y * 4 + w;                 // 0..511
    float4 c = *(const float4*)(Y + ((size_t)b * TT) * DD + lane * 4);
    float4 ww = *(const float4*)(w1 + (size_t)o * 256 + lane * 4);
    float s = c.x * ww.x + c.y * ww.y + c.z * ww.z + c.w * ww.w;
    #pragma unroll
    for (int off = 1; off < 64; off <<= 1) s += __shfl_xor(s, off);
    if (lane == 0) t1[b * 512 + o] = gelu_f(s + b1[o]);
}

// phase 2: out[b][o] = t1[b] . w2[o] + b2[o];  grid (BB, 128), block 256
__global__ __launch_bounds__(256) void head2_kernel(const float* __restrict__ t1,
                                                    const float* __restrict__ w2,
                                                    const float* __restrict__ b2,
                                                    float* __restrict__ out) {
    int b = blockIdx.x, w = threadIdx.x >> 6, lane = threadIdx.x & 63;
    int o = blockIdx.y * 4 + w;                 // 0..511
    const float* tp = t1 + b * 512 + lane * 8;
    const float* wp = w2 + (size_t)o * 512 + lane * 8;
    float4 a0 = *(const float4*)tp;
    float4 a1 = *(const float4*)(tp + 4);
    float4 b0 = *(const float4*)wp;
    float4 b1v = *(const float4*)(wp + 4);
    float s = a0.x * b0.x + a0.y * b0.y + a0.z * b0.z + a0.w * b0.w +
              a1.x * b1v.x + a1.y * b1v.y + a1.z * b1v.z + a1.w * b1v.w;
    #pragma unroll
    for (int off = 1; off < 64; off <<= 1) s += __shfl_xor(s, off);
    if (lane == 0) out[b * 512 + o] = s + b2[o];
}

// ---------------- launch ----------------
extern "C" void kernel_launch(void* const* d_in, const int* in_sizes, int n_in,
                              void* d_out, int out_size, void* d_ws, size_t ws_size,
                              hipStream_t stream) {
    (void)in_sizes; (void)n_in; (void)out_size; (void)ws_size;
    const float* expr     = (const float*)d_in[0];
    const float* gene_emb = (const float*)d_in[1];
    const float* ep_w1    = (const float*)d_in[2];
    const float* ep_b1    = (const float*)d_in[3];
    const float* ep_w2    = (const float*)d_in[4];
    const float* ep_b2    = (const float*)d_in[5];
    const float* clsv     = (const float*)d_in[6];
    const float* ln1_s    = (const float*)d_in[7];
    const float* ln1_b    = (const float*)d_in[8];
    const float* qkv_w    = (const float*)d_in[9];
    const float* qkv_b    = (const float*)d_in[10];
    const float* out_w    = (const float*)d_in[11];
    const float* out_b    = (const float*)d_in[12];
    const float* ln2_s    = (const float*)d_in[13];
    const float* ln2_b    = (const float*)d_in[14];
    const float* ff_w1    = (const float*)d_in[15];
    const float* ff_b1    = (const float*)d_in[16];
    const float* ff_w2    = (const float*)d_in[17];
    const float* ff_b2    = (const float*)d_in[18];
    const float* fn_s     = (const float*)d_in[19];
    const float* fn_b     = (const float*)d_in[20];
    const float* pr_w1    = (const float*)d_in[21];
    const float* pr_b1    = (const float*)d_in[22];
    const float* pr_w2    = (const float*)d_in[23];
    const float* pr_b2    = (const float*)d_in[24];
    float* outp = (float*)d_out;

    const size_t KVSZ = (size_t)32 * NT * 1024;

    // workspace layout
    float* x   = (float*)d_ws;                       // BT*256 f32
    float* VAL = x + (size_t)BT * 256;               // 8192*256 f32; reused as Vt + final-LN out
    ub16* y16   = (ub16*)(VAL + (size_t)8192 * 256);
    ub16* qkv16 = y16 + (size_t)BT * 256;
    ub16* att16 = qkv16 + (size_t)BT * 768;
    ub16* ff116 = att16 + (size_t)BT * 256;
    ub16* kc_h  = ff116 + (size_t)BT * 1024;
    ub16* wqkv  = kc_h + KVSZ;
    ub16* wout  = wqkv + (size_t)LL * 768 * 256;
    ub16* wff1  = wout + (size_t)LL * 256 * 256;
    ub16* wff2  = wff1 + (size_t)LL * 1024 * 256;
    ub16* wep2  = wff2 + (size_t)LL * 256 * 1024;
    int*  idxb  = (int*)(wep2 + (size_t)256 * 256);
    int*  cntb  = idxb + BB * KK;
    unsigned* prefwant = (unsigned*)(cntb + BB);
    unsigned* histg    = prefwant + BB * 2;
    int* blkcnt  = (int*)(histg + BB * 256);
    int* blkbase = blkcnt + BB * TCH * 2;
    float* t1f   = (float*)(blkbase + BB * TCH * 2);  // BB*512 f32
    ub16* H16 = kc_h;
    ub16* Kc  = kc_h;
    ub16* Vt  = (ub16*)VAL;

    // 1) top-K (multi-block radix select)
    topk_init<<<1, 1024, 0, stream>>>(prefwant, histg);
    for (int p = 3; p >= 0; --p) {
        topk_hist<<<dim3(BB, TCH), 1024, 0, stream>>>(expr, prefwant, histg, p);
        topk_select<<<BB, 64, 0, stream>>>(prefwant, histg, p);
    }
    topk_c1<<<dim3(BB, TCH), 1024, 0, stream>>>(expr, prefwant, blkcnt);
    topk_c2<<<BB, 64, 0, stream>>>(prefwant, blkcnt, blkbase, cntb);
    topk_c3<<<dim3(BB, TCH), 1024, 0, stream>>>(expr, prefwant, blkbase, idxb);

    // 2) weights -> bf16
    cvt_bf16_kernel<<<(LL*768*256 + 255)/256, 256, 0, stream>>>(qkv_w, wqkv, LL*768*256);
    cvt_bf16_kernel<<<(LL*256*256 + 255)/256, 256, 0, stream>>>(out_w, wout, LL*256*256);
    cvt_bf16_kernel<<<(LL*1024*256 + 255)/256, 256, 0, stream>>>(ff_w1, wff1, LL*1024*256);
    cvt_bf16_kernel<<<(LL*256*1024 + 255)/256, 256, 0, stream>>>(ff_w2, wff2, LL*256*1024);
    cvt_bf16_kernel<<<(256*256 + 255)/256, 256, 0, stream>>>(ep_w2, wep2, 256*256);

    // 3) token embeddings
    build_h_kernel<<<(BB * KK * DD) / 256, 256, 0, stream>>>(expr, idxb, cntb, ep_w1, ep_b1, H16);
    gemm_bt16<<<dim3(4, 128), 256, 0, stream>>>(H16, wep2, ep_b2, nullptr, VAL, nullptr,
                                                8192, 256, 256, 0, 0);
    assemble_kernel<<<BT, 256, 0, stream>>>(VAL, gene_emb, clsv, idxb, cntb, x);

    // 4) transformer layers
    for (int i = 0; i < LL; ++i) {
        ln_kernel<<<BT / 4, 256, 0, stream>>>(x, ln1_s + i * DD, ln1_b + i * DD, y16, nullptr);
        gemm_bn128<<<dim3(6, 129), 256, 0, stream>>>(y16, wqkv + (size_t)i * 768 * 256,
                                                     qkv_b + i * 768, qkv16,
                                                     BT, 768, 256, 0, 256);
        kvprep<<<dim3(BB * HH, 33), 256, 0, stream>>>(qkv16, Kc, Vt);
        attn_mfma7<<<dim3(BB * HH, NT), 256, 0, stream>>>(qkv16, Kc, Vt, cntb, att16);
        gemm_bt16<<<dim3(4, 129), 256, 0, stream>>>(att16, wout + (size_t)i * 256 * 256,
                                                    out_b + i * 256, x, x, nullptr,
                                                    BT, 256, 256, 0, 0);
        ln_kernel<<<BT / 4, 256, 0, stream>>>(x, ln2_s + i * DD, ln2_b + i * DD, y16, nullptr);
        gemm_bn128<<<dim3(8, 129), 256, 0, stream>>>(y16, wff1 + (size_t)i * 1024 * 256,
                                                     ff_b1 + i * 1024, ff116,
                                                     BT, 1024, 256, 1, 0);
        gemm_bt16<<<dim3(4, 129), 256, 0, stream>>>(ff116, wff2 + (size_t)i * 256 * 1024,
                                                    ff_b2 + i * 256, x, x, nullptr,
                                                    BT, 256, 1024, 0, 0);
    }

    // 5) final LN + head (wave-per-output, coalesced)
    ln_kernel<<<BT / 4, 256, 0, stream>>>(x, fn_s, fn_b, nullptr, VAL);
    head1_kernel<<<dim3(BB, 128), 256, 0, stream>>>(VAL, pr_w1, pr_b1, t1f);
    head2_kernel<<<dim3(BB, 128), 256, 0, stream>>>(t1f, pr_w2, pr_b2, outp);
}